// Round 23
// baseline (176.902 us; speedup 1.0000x reference)
//
#include <hip/hip_runtime.h>

// Hierarchical 3-level pooled MHA. Round 23: attn processes TWO q-tiles per
// block against one K/V stream (halves staging/barriers per MFMA). Per-q-tile
// compute is byte-identical to R20's proven sequence (liveness-minimal order);
// launch_bounds (256,3) caps 170 regs (peak ~160). Grid (32,8,3), XCD-pinned.
// All other kernels identical to R22 (best: 163.0 us).
// B=2, S=2048, D=1024, H=16, DH=64.

#define B_  2
#define S_  2048
#define D_  1024
#define H_  16
#define DH_ 64
#define THR2 10.0f   // defer-max threshold, base-2 domain

typedef short s8v __attribute__((ext_vector_type(8)));    // 8 bf16
typedef float f4v __attribute__((ext_vector_type(4)));
typedef float f16v __attribute__((ext_vector_type(16)));  // 32x32 accum
typedef unsigned int u32x2 __attribute__((ext_vector_type(2)));
typedef unsigned int u32x4 __attribute__((ext_vector_type(4)));

__device__ __forceinline__ unsigned cvtpk(float lo, float hi){
    unsigned r;
    asm volatile("v_cvt_pk_bf16_f32 %0, %1, %2" : "=v"(r) : "v"(lo), "v"(hi));
    return r;
}
__device__ __forceinline__ unsigned short f2bf1(float v){
    unsigned r;
    asm volatile("v_cvt_pk_bf16_f32 %0, %1, %2" : "=v"(r) : "v"(v), "v"(v));
    return (unsigned short)r;
}
__device__ __forceinline__ float bf2f(unsigned short h){
    union { unsigned u; float f; } v; v.u = ((unsigned)h) << 16;
    return v.f;
}
__device__ __forceinline__ float exp2_(float x){
    float r; asm("v_exp_f32 %0, %1" : "=v"(r) : "v"(x)); return r;
}
__device__ __forceinline__ float max3_(float a, float b, float c){
    float r; asm("v_max3_f32 %0, %1, %2, %3" : "=v"(r) : "v"(a), "v"(b), "v"(c));
    return r;
}
// v_permlane32_swap_b32 vdst, vsrc: vdst[32:63] <-> vsrc[0:31] (both updated).
__device__ __forceinline__ void pswap(unsigned &dst, unsigned &src){
    asm volatile("v_permlane32_swap_b32 %0, %1" : "+v"(dst), "+v"(src));
}
// three bf16x2 -> bf16x2 sum, single RNE repack (f32 adds)
__device__ __forceinline__ unsigned addpk3(unsigned x, unsigned y, unsigned z){
    union { unsigned u; float f; } xl, yl, zl, xh, yh, zh;
    xl.u = x << 16;          yl.u = y << 16;          zl.u = z << 16;
    xh.u = x & 0xFFFF0000u;  yh.u = y & 0xFFFF0000u;  zh.u = z & 0xFFFF0000u;
    return cvtpk(xl.f + yl.f + zl.f, xh.f + yh.f + zh.f);
}
// XOR-swizzled byte offset of 16B block kb in row `row` of a [rows][64bf16] tile.
__device__ __forceinline__ int swz(int row, int kb){
    return row*128 + (((kb) ^ (row & 7) ^ ((row >> 3) & 7)) << 4);
}
// async 16B global->LDS; LDS dest = wave-uniform base + lane*16 (linear)
__device__ __forceinline__ void gld16(const void* g, void* l){
    __builtin_amdgcn_global_load_lds(
        (const __attribute__((address_space(1))) unsigned int*)g,
        (__attribute__((address_space(3))) unsigned int*)l, 16, 0, 0);
}

// ---------------- W transpose + bf16 convert: Wt[n][k] = bf16(W[k][n]) ----------------
__global__ __launch_bounds__(256) void wtrans(
    const float* __restrict__ W0, const float* __restrict__ W1,
    const float* __restrict__ W2, const float* __restrict__ W3,
    unsigned short* __restrict__ T0, unsigned short* __restrict__ T1,
    unsigned short* __restrict__ T2, unsigned short* __restrict__ T3)
{
    __shared__ float tl[32][33];
    const float* W = blockIdx.z==0?W0: blockIdx.z==1?W1: blockIdx.z==2?W2:W3;
    unsigned short* T = blockIdx.z==0?T0: blockIdx.z==1?T1: blockIdx.z==2?T2:T3;
    const int t = threadIdx.x;
    const int bk = blockIdx.x*32, bn = blockIdx.y*32;
    {
        int row = t>>3, c4 = (t&7)*4;
        float4 v = *(const float4*)&W[(size_t)(bk+row)*D_ + bn + c4];
        tl[row][c4+0]=v.x; tl[row][c4+1]=v.y; tl[row][c4+2]=v.z; tl[row][c4+3]=v.w;
    }
    __syncthreads();
    {
        int n = t>>3, k4 = (t&7)*4;
        unsigned a = cvtpk(tl[k4+0][n], tl[k4+1][n]);
        unsigned b = cvtpk(tl[k4+2][n], tl[k4+3][n]);
        u32x2 pk = {a, b};
        *(u32x2*)&T[(size_t)(bn+n)*D_ + bk + k4] = pk;
    }
}

// ---------------- z-merged QKV projection GEMM (128^2 dbuf) + fused K pools ----------------
// Grid (32, 8, 3): blockIdx.x = ROW panel (XCD-pins A), blockIdx.y = col panel.
__global__ __launch_bounds__(256) void gemm_qkv3(
    const float* __restrict__ Aq, const float* __restrict__ Ak, const float* __restrict__ Avv,
    const unsigned short* __restrict__ Wq_, const unsigned short* __restrict__ Wk_,
    const unsigned short* __restrict__ Wv_,
    const float* __restrict__ bq_, const float* __restrict__ bk_, const float* __restrict__ bv_,
    unsigned short* __restrict__ Oq, unsigned short* __restrict__ Ok,
    unsigned short* __restrict__ Ov,
    unsigned short* __restrict__ K1, unsigned short* __restrict__ K2,
    float scale_q)
{
    const int z = blockIdx.z;
    const float* Af = z==0?Aq : z==1?Ak : Avv;
    const unsigned short* Btw = z==0?Wq_ : z==1?Wk_ : Wv_;
    const float* bias = z==0?bq_ : z==1?bk_ : bv_;
    unsigned short* C = z==0?Oq : z==1?Ok : Ov;
    const float scale = z==0? scale_q : 1.0f;

    const int N_ = D_, K_ = D_;
    __shared__ __align__(16) char lds[65536];    // dbuf: [cur][A 16K | B 16K]
    const int t = threadIdx.x;
    const int l = t & 63, wvi = t>>6, g = l>>4, x = l&15;
    const int wr = wvi>>1, wc = wvi&1;
    const int br = blockIdx.x*128, bc = blockIdx.y*128;   // TRANSPOSED grid

    int rw[4], bl[4];
    #pragma unroll
    for (int p=0;p<4;++p){ int u = t + 256*p; rw[p] = u>>3; bl[p] = u&7; }

    f4v acc[4][4];
    #pragma unroll
    for (int i=0;i<4;++i)
        #pragma unroll
        for (int j=0;j<4;++j) acc[i][j] = (f4v){0.f,0.f,0.f,0.f};

    float4 alo[4], ahi[4]; s8v brg[4];
    #pragma unroll
    for (int p=0;p<4;++p){
        const float* ap = Af + (size_t)(br+rw[p])*K_ + bl[p]*8;
        alo[p] = *(const float4*)ap; ahi[p] = *(const float4*)(ap+4);
        brg[p] = *(const s8v*)(Btw + (size_t)(bc+rw[p])*K_ + bl[p]*8);
    }

    int cur = 0;
    for (int kt=0; kt<K_; kt+=64){
        char* AsB = lds + cur*32768;
        char* BsB = AsB + 16384;
        #pragma unroll
        for (int p=0;p<4;++p){
            uint4 pk;
            pk.x = cvtpk(alo[p].x, alo[p].y); pk.y = cvtpk(alo[p].z, alo[p].w);
            pk.z = cvtpk(ahi[p].x, ahi[p].y); pk.w = cvtpk(ahi[p].z, ahi[p].w);
            *(uint4*)(AsB + swz(rw[p], bl[p])) = pk;
            *(s8v*)(BsB + swz(rw[p], bl[p])) = brg[p];
        }
        if (kt + 64 < K_){
            #pragma unroll
            for (int p=0;p<4;++p){
                const float* ap = Af + (size_t)(br+rw[p])*K_ + (kt+64) + bl[p]*8;
                alo[p] = *(const float4*)ap; ahi[p] = *(const float4*)(ap+4);
                brg[p] = *(const s8v*)(Btw + (size_t)(bc+rw[p])*K_ + (kt+64) + bl[p]*8);
            }
        }
        __syncthreads();
        #pragma unroll
        for (int c=0;c<2;++c){
            s8v af[4], bf[4];
            #pragma unroll
            for (int fm=0; fm<4; ++fm)
                af[fm] = *(const s8v*)(AsB + swz(wr*64+fm*16+x, c*4+g));
            #pragma unroll
            for (int fn=0; fn<4; ++fn)
                bf[fn] = *(const s8v*)(BsB + swz(wc*64+fn*16+x, c*4+g));
            __builtin_amdgcn_s_setprio(1);
            #pragma unroll
            for (int fm=0; fm<4; ++fm)
                #pragma unroll
                for (int fn=0; fn<4; ++fn)
                    acc[fm][fn] = __builtin_amdgcn_mfma_f32_16x16x32_bf16(
                        af[fm], bf[fn], acc[fm][fn], 0,0,0);
            __builtin_amdgcn_s_setprio(0);
        }
        cur ^= 1;
    }

    #pragma unroll
    for (int fn=0; fn<4; ++fn){
        int col = bc + wc*64 + fn*16 + x;
        float bv = bias[col];
        #pragma unroll
        for (int fm=0; fm<4; ++fm){
            int row0 = br + wr*64 + fm*16 + g*4;
            float v0 = acc[fm][fn][0] + bv;
            float v1 = acc[fm][fn][1] + bv;
            float v2 = acc[fm][fn][2] + bv;
            float v3 = acc[fm][fn][3] + bv;
            int bI = row0>>11, sI = row0 & (S_-1);
            int hI = col>>6,  dhI = col & (DH_-1);
            size_t bh = (size_t)(bI*H_ + hI);
            if (z != 2){
                unsigned short* p0 = C + (bh*S_ + sI)*DH_ + dhI;
                p0[0]      = f2bf1(v0*scale);
                p0[DH_]    = f2bf1(v1*scale);
                p0[2*DH_]  = f2bf1(v2*scale);
                p0[3*DH_]  = f2bf1(v3*scale);
                if (z == 1){   // fused K pools (coalesced 32B segments, exact algebra)
                    unsigned short* p1 = K1 + (bh*(S_/2) + (sI>>1))*DH_ + dhI;
                    p1[0]   = f2bf1((v0+v1)*0.5f);
                    p1[DH_] = f2bf1((v2+v3)*0.5f);
                    K2[(bh*(S_/4) + (sI>>2))*DH_ + dhI] = f2bf1((v0+v1+v2+v3)*0.25f);
                }
            } else {   // V: [B,H,DH,S], 4 consecutive tokens -> 8B store
                u32x2 pk;
                pk.x = cvtpk(v0, v1);
                pk.y = cvtpk(v2, v3);
                *(u32x2*)&C[(bh*DH_+dhI)*S_ + sI] = pk;
            }
        }
    }
}

// ---------------- V pools (both levels) from V0 [BH*DH][S]: fully coalesced ----------------
__global__ __launch_bounds__(256) void pool_v(
    const unsigned short* __restrict__ V0, unsigned short* __restrict__ V1,
    unsigned short* __restrict__ V2)
{
    int idx = blockIdx.x * 256 + threadIdx.x;       // 0 .. BH*DH*S/8-1
    int row = idx >> 8;                             // S/8 = 256 chunks per row
    int c8  = idx & 255;
    union { u32x4 u; unsigned short hh[8]; } a;
    a.u = *(const u32x4*)&V0[((size_t)row << 11) + c8*8];
    float m01 = 0.5f*(bf2f(a.hh[0])+bf2f(a.hh[1]));
    float m23 = 0.5f*(bf2f(a.hh[2])+bf2f(a.hh[3]));
    float m45 = 0.5f*(bf2f(a.hh[4])+bf2f(a.hh[5]));
    float m67 = 0.5f*(bf2f(a.hh[6])+bf2f(a.hh[7]));
    u32x2 p1; p1.x = cvtpk(m01, m23); p1.y = cvtpk(m45, m67);
    *(u32x2*)&V1[((size_t)row << 10) + c8*4] = p1;
    *(unsigned*)&V2[((size_t)row << 9) + c8*2] =
        cvtpk(0.5f*(m01+m23), 0.5f*(m45+m67));
}

// ---------------- final GEMM BM=128,BN=64: out = (a0+a1+a2)_bf16 @ Wto^T + bias ----------------
// Grid (32, 16): blockIdx.x = ROW panel (XCD-pins A), blockIdx.y = col panel.
__global__ __launch_bounds__(256) void gemm_sum(
    const unsigned short* __restrict__ A0, const unsigned short* __restrict__ A1,
    const unsigned short* __restrict__ A2, const unsigned short* __restrict__ Btw,
    const float* __restrict__ bias, float* __restrict__ C)
{
    const int N_ = D_, K_ = D_;
    __shared__ __align__(16) char lds[49152];   // dbuf: [cur][A 16K | B 8K]
    const int t = threadIdx.x;
    const int l = t & 63, wvi = t>>6, g = l>>4, x = l&15;
    const int wr = wvi>>1, wc = wvi&1;
    const int br = blockIdx.x*128, bc = blockIdx.y*64;    // TRANSPOSED grid

    int rw[4], bl[4];
    #pragma unroll
    for (int p=0;p<4;++p){ int u = t + 256*p; rw[p] = u>>3; bl[p] = u&7; }
    int bw[2], bb[2];
    #pragma unroll
    for (int p=0;p<2;++p){ int u = t + 256*p; bw[p] = u>>3; bb[p] = u&7; }

    f4v acc[4][2];
    #pragma unroll
    for (int i=0;i<4;++i){ acc[i][0] = (f4v){0,0,0,0}; acc[i][1] = (f4v){0,0,0,0}; }

    u32x4 a0r[4], a1r[4], a2r[4]; s8v brg[2];
    #pragma unroll
    for (int p=0;p<4;++p){
        size_t off = (size_t)(br+rw[p])*K_ + bl[p]*8;
        a0r[p] = *(const u32x4*)(A0 + off);
        a1r[p] = *(const u32x4*)(A1 + off);
        a2r[p] = *(const u32x4*)(A2 + off);
    }
    #pragma unroll
    for (int p=0;p<2;++p)
        brg[p] = *(const s8v*)(Btw + (size_t)(bc+bw[p])*K_ + bb[p]*8);

    int cur = 0;
    for (int kt=0; kt<K_; kt+=64){
        char* AsB = lds + cur*24576;
        char* BsB = AsB + 16384;
        #pragma unroll
        for (int p=0;p<4;++p){
            uint4 pk;
            pk.x = addpk3(a0r[p].x, a1r[p].x, a2r[p].x);
            pk.y = addpk3(a0r[p].y, a1r[p].y, a2r[p].y);
            pk.z = addpk3(a0r[p].z, a1r[p].z, a2r[p].z);
            pk.w = addpk3(a0r[p].w, a1r[p].w, a2r[p].w);
            *(uint4*)(AsB + swz(rw[p], bl[p])) = pk;
        }
        #pragma unroll
        for (int p=0;p<2;++p)
            *(s8v*)(BsB + swz(bw[p], bb[p])) = brg[p];
        if (kt + 64 < K_){
            #pragma unroll
            for (int p=0;p<4;++p){
                size_t off = (size_t)(br+rw[p])*K_ + (kt+64) + bl[p]*8;
                a0r[p] = *(const u32x4*)(A0 + off);
                a1r[p] = *(const u32x4*)(A1 + off);
                a2r[p] = *(const u32x4*)(A2 + off);
            }
            #pragma unroll
            for (int p=0;p<2;++p)
                brg[p] = *(const s8v*)(Btw + (size_t)(bc+bw[p])*K_ + (kt+64) + bb[p]*8);
        }
        __syncthreads();
        #pragma unroll
        for (int c=0;c<2;++c){
            s8v af[4], bf[2];
            #pragma unroll
            for (int fm=0; fm<4; ++fm)
                af[fm] = *(const s8v*)(AsB + swz(wr*64+fm*16+x, c*4+g));
            #pragma unroll
            for (int fn=0; fn<2; ++fn)
                bf[fn] = *(const s8v*)(BsB + swz(wc*32+fn*16+x, c*4+g));
            __builtin_amdgcn_s_setprio(1);
            #pragma unroll
            for (int fm=0; fm<4; ++fm)
                #pragma unroll
                for (int fn=0; fn<2; ++fn)
                    acc[fm][fn] = __builtin_amdgcn_mfma_f32_16x16x32_bf16(
                        af[fm], bf[fn], acc[fm][fn], 0,0,0);
            __builtin_amdgcn_s_setprio(0);
        }
        cur ^= 1;
    }

    #pragma unroll
    for (int fn=0; fn<2; ++fn){
        int col = bc + wc*32 + fn*16 + x;
        float bv = bias[col];
        #pragma unroll
        for (int fm=0; fm<4; ++fm){
            int row0 = br + wr*64 + fm*16 + g*4;
            #pragma unroll
            for (int r=0;r<4;++r)
                C[(size_t)(row0+r)*N_ + col] = acc[fm][fn][r] + bv;
        }
    }
}

// ---------------- MFMA flash attention: 2 q-tiles per block, shared K/V stream ----------------
// Per-tile compute for one q-tile (R20's liveness-minimal order). s0/s1 are
// produced and fully consumed inside the macro — never live across it.
#define ATTN_QTILE(QF0,QF1,QF2,QF3,MI,LI,O0,O1)                                   \
    {                                                                              \
        f16v s0, s1;                                                               \
        _Pragma("unroll")                                                          \
        for (int r=0;r<16;++r){ s0[r]=0.f; s1[r]=0.f; }                            \
        {                                                                          \
            s8v k00 = *(const s8v*)(kb_ + swz(q,    0*2+hi));                      \
            s8v k01 = *(const s8v*)(kb_ + swz(q,    1*2+hi));                      \
            s8v k10 = *(const s8v*)(kb_ + swz(32+q, 0*2+hi));                      \
            s8v k11 = *(const s8v*)(kb_ + swz(32+q, 1*2+hi));                      \
            __builtin_amdgcn_s_setprio(1);                                         \
            s0 = __builtin_amdgcn_mfma_f32_32x32x16_bf16(k00, QF0, s0, 0,0,0);     \
            s1 = __builtin_amdgcn_mfma_f32_32x32x16_bf16(k10, QF0, s1, 0,0,0);     \
            s0 = __builtin_amdgcn_mfma_f32_32x32x16_bf16(k01, QF1, s0, 0,0,0);     \
            s1 = __builtin_amdgcn_mfma_f32_32x32x16_bf16(k11, QF1, s1, 0,0,0);     \
            __builtin_amdgcn_s_setprio(0);                                         \
        }                                                                          \
        {                                                                          \
            s8v k02 = *(const s8v*)(kb_ + swz(q,    2*2+hi));                      \
            s8v k03 = *(const s8v*)(kb_ + swz(q,    3*2+hi));                      \
            s8v k12 = *(const s8v*)(kb_ + swz(32+q, 2*2+hi));                      \
            s8v k13 = *(const s8v*)(kb_ + swz(32+q, 3*2+hi));                      \
            __builtin_amdgcn_s_setprio(1);                                         \
            s0 = __builtin_amdgcn_mfma_f32_32x32x16_bf16(k02, QF2, s0, 0,0,0);     \
            s1 = __builtin_amdgcn_mfma_f32_32x32x16_bf16(k12, QF2, s1, 0,0,0);     \
            s0 = __builtin_amdgcn_mfma_f32_32x32x16_bf16(k03, QF3, s0, 0,0,0);     \
            s1 = __builtin_amdgcn_mfma_f32_32x32x16_bf16(k13, QF3, s1, 0,0,0);     \
            __builtin_amdgcn_s_setprio(0);                                         \
        }                                                                          \
        float ca = max3_(s0[0], s0[1], s0[2]);                                     \
        ca = max3_(ca, s0[3], s0[4]);                                              \
        ca = max3_(ca, s0[5], s0[6]);                                              \
        ca = fmaxf(ca, s0[7]);                                                     \
        float cb = max3_(s0[8], s0[9], s0[10]);                                    \
        cb = max3_(cb, s0[11], s0[12]);                                            \
        cb = max3_(cb, s0[13], s0[14]);                                            \
        cb = fmaxf(cb, s0[15]);                                                    \
        float cc = max3_(s1[0], s1[1], s1[2]);                                     \
        cc = max3_(cc, s1[3], s1[4]);                                              \
        cc = max3_(cc, s1[5], s1[6]);                                              \
        cc = fmaxf(cc, s1[7]);                                                     \
        float cd = max3_(s1[8], s1[9], s1[10]);                                    \
        cd = max3_(cd, s1[11], s1[12]);                                            \
        cd = max3_(cd, s1[13], s1[14]);                                            \
        cd = fmaxf(cd, s1[15]);                                                    \
        float pm = fmaxf(max3_(ca, cb, cc), cd);                                   \
        pm = fmaxf(pm, __shfl_xor(pm, 32, 64));                                    \
        if (__any(pm > MI + THR2)) {                                               \
            float mn = fmaxf(MI, pm);                                              \
            float corr = exp2_(MI - mn);                                           \
            MI = mn;                                                               \
            LI *= corr;                                                            \
            _Pragma("unroll")                                                      \
            for (int r=0;r<16;++r){                                                \
                float cbc = __shfl(corr, ((r&3)+8*(r>>2)) + 4*hi, 64);             \
                O0[r] *= cbc; O1[r] *= cbc;                                        \
            }                                                                      \
        }                                                                          \
        _Pragma("unroll")                                                          \
        for (int r=0;r<16;++r) s0[r] = exp2_(s0[r]-MI);                            \
        _Pragma("unroll")                                                          \
        for (int r=0;r<16;++r) s1[r] = exp2_(s1[r]-MI);                            \
        {                                                                          \
            float r0 = s0[0]+s0[4],  r1 = s0[1]+s0[5];                             \
            float r2 = s0[2]+s0[6],  r3 = s0[3]+s0[7];                             \
            float r4 = s1[0]+s1[4],  r5 = s1[1]+s1[5];                             \
            float r6 = s1[2]+s1[6],  r7 = s1[3]+s1[7];                             \
            r0 += s0[8]+s0[12];  r1 += s0[9]+s0[13];                               \
            r2 += s0[10]+s0[14]; r3 += s0[11]+s0[15];                              \
            r4 += s1[8]+s1[12];  r5 += s1[9]+s1[13];                               \
            r6 += s1[10]+s1[14]; r7 += s1[11]+s1[15];                              \
            float rs = ((r0+r1)+(r2+r3)) + ((r4+r5)+(r6+r7));                      \
            rs += __shfl_xor(rs, 32, 64);                                          \
            LI += rs;                                                              \
        }                                                                          \
        unsigned a0 = cvtpk(s0[0], s0[1]),  a1 = cvtpk(s0[2], s0[3]);              \
        unsigned b0 = cvtpk(s0[4], s0[5]),  b1 = cvtpk(s0[6], s0[7]);              \
        pswap(a0, b0); pswap(a1, b1);                                              \
        unsigned c0 = cvtpk(s0[8], s0[9]),  c1 = cvtpk(s0[10], s0[11]);            \
        unsigned d0 = cvtpk(s0[12], s0[13]),d1 = cvtpk(s0[14], s0[15]);            \
        pswap(c0, d0); pswap(c1, d1);                                              \
        unsigned e0 = cvtpk(s1[0], s1[1]),  e1 = cvtpk(s1[2], s1[3]);              \
        unsigned f0 = cvtpk(s1[4], s1[5]),  f1 = cvtpk(s1[6], s1[7]);              \
        pswap(e0, f0); pswap(e1, f1);                                              \
        unsigned g0 = cvtpk(s1[8], s1[9]),  g1 = cvtpk(s1[10], s1[11]);            \
        unsigned h0 = cvtpk(s1[12], s1[13]),h1 = cvtpk(s1[14], s1[15]);            \
        pswap(g0, h0); pswap(g1, h1);                                              \
        union { u32x4 u; s8v s; } pf0, pf1, pf2, pf3;                              \
        pf0.u = (u32x4){a0, a1, b0, b1};                                           \
        pf1.u = (u32x4){c0, c1, d0, d1};                                           \
        pf2.u = (u32x4){e0, e1, f0, f1};                                           \
        pf3.u = (u32x4){g0, g1, h0, h1};                                           \
        {                                                                          \
            s8v v00 = *(const s8v*)(vb_ + swz(q,    0*2+hi));                      \
            s8v v01 = *(const s8v*)(vb_ + swz(q,    1*2+hi));                      \
            s8v v10 = *(const s8v*)(vb_ + swz(32+q, 0*2+hi));                      \
            s8v v11 = *(const s8v*)(vb_ + swz(32+q, 1*2+hi));                      \
            __builtin_amdgcn_s_setprio(1);                                         \
            O0 = __builtin_amdgcn_mfma_f32_32x32x16_bf16(pf0.s, v00, O0, 0,0,0);   \
            O1 = __builtin_amdgcn_mfma_f32_32x32x16_bf16(pf0.s, v10, O1, 0,0,0);   \
            O0 = __builtin_amdgcn_mfma_f32_32x32x16_bf16(pf1.s, v01, O0, 0,0,0);   \
            O1 = __builtin_amdgcn_mfma_f32_32x32x16_bf16(pf1.s, v11, O1, 0,0,0);   \
            __builtin_amdgcn_s_setprio(0);                                         \
        }                                                                          \
        {                                                                          \
            s8v v02 = *(const s8v*)(vb_ + swz(q,    2*2+hi));                      \
            s8v v03 = *(const s8v*)(vb_ + swz(q,    3*2+hi));                      \
            s8v v12 = *(const s8v*)(vb_ + swz(32+q, 2*2+hi));                      \
            s8v v13 = *(const s8v*)(vb_ + swz(32+q, 3*2+hi));                      \
            __builtin_amdgcn_s_setprio(1);                                         \
            O0 = __builtin_amdgcn_mfma_f32_32x32x16_bf16(pf2.s, v02, O0, 0,0,0);   \
            O1 = __builtin_amdgcn_mfma_f32_32x32x16_bf16(pf2.s, v12, O1, 0,0,0);   \
            O0 = __builtin_amdgcn_mfma_f32_32x32x16_bf16(pf3.s, v03, O0, 0,0,0);   \
            O1 = __builtin_amdgcn_mfma_f32_32x32x16_bf16(pf3.s, v13, O1, 0,0,0);   \
            __builtin_amdgcn_s_setprio(0);                                         \
        }                                                                          \
    }

__global__ __launch_bounds__(256, 3) void attn_mfma15(
    const unsigned short* __restrict__ qh,
    const unsigned short* __restrict__ kh0, const unsigned short* __restrict__ kh1,
    const unsigned short* __restrict__ kh2,
    const unsigned short* __restrict__ vt0, const unsigned short* __restrict__ vt1,
    const unsigned short* __restrict__ vt2,
    const float* __restrict__ wlv,
    unsigned short* __restrict__ acc0, unsigned short* __restrict__ acc1,
    unsigned short* __restrict__ acc2)
{
    __shared__ __align__(16) char ldsA[32768];   // [buf][ K 8KB | V 8KB ]
    const int t = threadIdx.x, l = t&63, wv = t>>6, q = l&31, hi = l>>5;
    const int bh_ = blockIdx.x;                  // b*H + h  (XCD = bh%8)
    const int h = bh_ & (H_-1), b = bh_ >> 4;
    const int qtA = blockIdx.y*2, qtB = qtA + 1;
    const int lvl = blockIdx.z;
    const int nt = 32 >> lvl;
    const unsigned short* kp  = lvl==0 ? kh0 : (lvl==1 ? kh1 : kh2);
    const unsigned short* vpt = lvl==0 ? vt0 : (lvl==1 ? vt1 : vt2);
    unsigned short* accOut    = lvl==0 ? acc0 : (lvl==1 ? acc1 : acc2);

    const float w0 = wlv[0], w1 = wlv[1], w2 = wlv[2];
    const float wl = wlv[lvl] / (w0 + w1 + w2);

    const unsigned short* qpA =
        qh + (((size_t)(b*H_+h))*S_ + (size_t)qtA*128 + wv*32 + q)*DH_ + hi*8;
    s8v qfA0 = *(const s8v*)(qpA);
    s8v qfA1 = *(const s8v*)(qpA + 16);
    s8v qfA2 = *(const s8v*)(qpA + 32);
    s8v qfA3 = *(const s8v*)(qpA + 48);
    const unsigned short* qpB = qpA + (size_t)128*DH_;
    s8v qfB0 = *(const s8v*)(qpB);
    s8v qfB1 = *(const s8v*)(qpB + 16);
    s8v qfB2 = *(const s8v*)(qpB + 32);
    s8v qfB3 = *(const s8v*)(qpB + 48);

    const int Sl = nt*64;
    const char* gK = (const char*)(kp + (size_t)(b*H_+h)*Sl*DH_);
    const char* gV = (const char*)(vpt + (size_t)(b*H_+h)*DH_*Sl);

    // per-lane inverse-swizzled source offsets (chunk bases R0=wv*8, R1=32+wv*8)
    const int lr = l>>3, lc = l&7;
    const int kb0 = lc ^ lr ^ wv;          // (R0>>3)&7 == wv
    const int kb1 = lc ^ lr ^ (wv+4);      // (R1>>3)&7 == wv+4
    const int kOffG0 = (((wv*8+lr)*DH_)    + kb0*8)*2;
    const int kOffG1 = (((32+wv*8+lr)*DH_) + kb1*8)*2;
    const int vOffG0 = ((wv*8+lr)*Sl    + kb0*8)*2;
    const int vOffG1 = ((32+wv*8+lr)*Sl + kb1*8)*2;
    const int ldsOff0 = wv*1024, ldsOff1 = 4096 + wv*1024;

    float mA = -1e30f, lA = 0.f, mB = -1e30f, lB = 0.f;
    f16v oA0, oA1, oB0, oB1;
    #pragma unroll
    for (int r=0;r<16;++r){ oA0[r]=0.f; oA1[r]=0.f; oB0[r]=0.f; oB1[r]=0.f; }

    // prologue: stage tile 0 into buf 0
    {
        char* kB = ldsA;           char* vB = ldsA + 8192;
        gld16(gK + kOffG0, kB + ldsOff0);
        gld16(gK + kOffG1, kB + ldsOff1);
        gld16(gV + vOffG0, vB + ldsOff0);
        gld16(gV + vOffG1, vB + ldsOff1);
    }

    int cur = 0;
    for (int kt = 0; kt < nt; ++kt) {
        asm volatile("s_waitcnt vmcnt(0)" ::: "memory");
        __syncthreads();                       // tile kt fully landed, prev reads done
        if (kt + 1 < nt) {                     // T14: next tile flies under compute
            char* kB = ldsA + (cur^1)*16384;
            char* vB = kB + 8192;
            gld16(gK + (size_t)(kt+1)*64*DH_*2 + kOffG0, kB + ldsOff0);
            gld16(gK + (size_t)(kt+1)*64*DH_*2 + kOffG1, kB + ldsOff1);
            gld16(gV + (size_t)(kt+1)*128      + vOffG0, vB + ldsOff0);
            gld16(gV + (size_t)(kt+1)*128      + vOffG1, vB + ldsOff1);
        }
        char* kb_ = ldsA + cur*16384;
        char* vb_ = kb_ + 8192;

        ATTN_QTILE(qfA0,qfA1,qfA2,qfA3, mA, lA, oA0, oA1)
        ATTN_QTILE(qfB0,qfB1,qfB2,qfB3, mB, lB, oB0, oB1)

        cur ^= 1;
    }

    #pragma unroll
    for (int r=0;r<16;++r){
        int qrow = ((r&3)+8*(r>>2)) + 4*hi;
        float lbA = __shfl(lA, qrow, 64);
        float scA = wl / lbA;
        size_t rowA = (size_t)b*S_ + (size_t)qtA*128 + wv*32 + qrow;
        accOut[rowA*D_ + h*DH_ + q]      = f2bf1(oA0[r] * scA);
        accOut[rowA*D_ + h*DH_ + 32 + q] = f2bf1(oA1[r] * scA);
        float lbB = __shfl(lB, qrow, 64);
        float scB = wl / lbB;
        size_t rowB = rowA + 128;
        accOut[rowB*D_ + h*DH_ + q]      = f2bf1(oB0[r] * scB);
        accOut[rowB*D_ + h*DH_ + 32 + q] = f2bf1(oB1[r] * scB);
    }
}

// ---------------- launch ----------------
extern "C" void kernel_launch(void* const* d_in, const int* in_sizes, int n_in,
                              void* d_out, int out_size, void* d_ws, size_t ws_size,
                              hipStream_t stream)
{
    const float* query = (const float*)d_in[0];
    const float* key   = (const float*)d_in[1];
    const float* value = (const float*)d_in[2];
    const float* Wq = (const float*)d_in[3];  const float* bq = (const float*)d_in[4];
    const float* Wk = (const float*)d_in[5];  const float* bk = (const float*)d_in[6];
    const float* Wv = (const float*)d_in[7];  const float* bv = (const float*)d_in[8];
    const float* Wo = (const float*)d_in[9];  const float* bo = (const float*)d_in[10];
    const float* wlv = (const float*)d_in[11];

    char* w = (char*)d_ws;
    unsigned short* qhb  = (unsigned short*)(w);             // 8 MB [B,H,S,DH]
    unsigned short* khb0 = (unsigned short*)(w + 8388608);   // 8 MB [B,H,S,DH]
    unsigned short* khb1 = (unsigned short*)(w + 16777216);  // 4 MB
    unsigned short* khb2 = (unsigned short*)(w + 20971520);  // 2 MB
    unsigned short* vtb0 = (unsigned short*)(w + 23068672);  // 8 MB [B,H,DH,S]
    unsigned short* vtb1 = (unsigned short*)(w + 31457280);  // 4 MB
    unsigned short* vtb2 = (unsigned short*)(w + 35651584);  // 2 MB
    unsigned short* Wto  = (unsigned short*)(w + 37748736);  // 2 MB
    unsigned short* Wtq  = (unsigned short*)(w + 39845888);  // 2 MB (dead after proj)
    unsigned short* Wtk  = (unsigned short*)(w + 41943040);  // 2 MB (dead after proj)
    unsigned short* Wtv  = (unsigned short*)(w + 44040192);  // 2 MB (dead after proj)
    unsigned short* acc0 = (unsigned short*)(w + 39845888);  // 8 MB, overlaps Wtq..Wtv
    unsigned short* acc1 = (unsigned short*)(w + 48234496);  // 8 MB
    unsigned short* acc2 = (unsigned short*)(w + 56623104);  // 8 MB -> end 65,011,712

    dim3 bb(256);
    wtrans<<<dim3(32,32,4), bb, 0, stream>>>(Wq, Wk, Wv, Wo, Wtq, Wtk, Wtv, Wto);

    const float scale_q = 0.125f * 1.44269504088896f;   // 1/sqrt(DH) * log2(e)
    gemm_qkv3<<<dim3(32, 8, 3), bb, 0, stream>>>(query, key, value,
                                                 Wtq, Wtk, Wtv, bq, bk, bv,
                                                 qhb, khb0, vtb0,
                                                 khb1, khb2, scale_q);

    // V pools: BH*DH*S/8 threads = 524288 -> 2048 blocks, fully coalesced
    pool_v<<<2048, bb, 0, stream>>>(vtb0, vtb1, vtb2);

    attn_mfma15<<<dim3(32, 8, 3), bb, 0, stream>>>(qhb, khb0, khb1, khb2,
                                                   vtb0, vtb1, vtb2, wlv,
                                                   acc0, acc1, acc2);

    gemm_sum<<<dim3(32, 16), bb, 0, stream>>>(acc0, acc1, acc2, Wto, bo, (float*)d_out);
}

// Round 24
// 162.636 us; speedup vs baseline: 1.0877x; 1.0877x over previous
//
#include <hip/hip_runtime.h>

// Hierarchical 3-level pooled MHA. Round 24: lock in the best measured config
// (= R20/R22, 162.9-163.0 us, reproduced twice). R19/R21 (liveness) and R23
// (occupancy) all regressed; the R20 design point (64 VGPR, 3 waves/SIMD,
// liveness-minimal order, XCD-pinned grids) is the robust local optimum.
// B=2, S=2048, D=1024, H=16, DH=64.

#define B_  2
#define S_  2048
#define D_  1024
#define H_  16
#define DH_ 64
#define THR2 10.0f   // defer-max threshold, base-2 domain

typedef short s8v __attribute__((ext_vector_type(8)));    // 8 bf16
typedef float f4v __attribute__((ext_vector_type(4)));
typedef float f16v __attribute__((ext_vector_type(16)));  // 32x32 accum
typedef unsigned int u32x2 __attribute__((ext_vector_type(2)));
typedef unsigned int u32x4 __attribute__((ext_vector_type(4)));

__device__ __forceinline__ unsigned cvtpk(float lo, float hi){
    unsigned r;
    asm volatile("v_cvt_pk_bf16_f32 %0, %1, %2" : "=v"(r) : "v"(lo), "v"(hi));
    return r;
}
__device__ __forceinline__ unsigned short f2bf1(float v){
    unsigned r;
    asm volatile("v_cvt_pk_bf16_f32 %0, %1, %2" : "=v"(r) : "v"(v), "v"(v));
    return (unsigned short)r;
}
__device__ __forceinline__ float bf2f(unsigned short h){
    union { unsigned u; float f; } v; v.u = ((unsigned)h) << 16;
    return v.f;
}
__device__ __forceinline__ float exp2_(float x){
    float r; asm("v_exp_f32 %0, %1" : "=v"(r) : "v"(x)); return r;
}
__device__ __forceinline__ float max3_(float a, float b, float c){
    float r; asm("v_max3_f32 %0, %1, %2, %3" : "=v"(r) : "v"(a), "v"(b), "v"(c));
    return r;
}
// v_permlane32_swap_b32 vdst, vsrc: vdst[32:63] <-> vsrc[0:31] (both updated).
__device__ __forceinline__ void pswap(unsigned &dst, unsigned &src){
    asm volatile("v_permlane32_swap_b32 %0, %1" : "+v"(dst), "+v"(src));
}
// three bf16x2 -> bf16x2 sum, single RNE repack (f32 adds)
__device__ __forceinline__ unsigned addpk3(unsigned x, unsigned y, unsigned z){
    union { unsigned u; float f; } xl, yl, zl, xh, yh, zh;
    xl.u = x << 16;          yl.u = y << 16;          zl.u = z << 16;
    xh.u = x & 0xFFFF0000u;  yh.u = y & 0xFFFF0000u;  zh.u = z & 0xFFFF0000u;
    return cvtpk(xl.f + yl.f + zl.f, xh.f + yh.f + zh.f);
}
// XOR-swizzled byte offset of 16B block kb in row `row` of a [rows][64bf16] tile.
__device__ __forceinline__ int swz(int row, int kb){
    return row*128 + (((kb) ^ (row & 7) ^ ((row >> 3) & 7)) << 4);
}
// async 16B global->LDS; LDS dest = wave-uniform base + lane*16 (linear)
__device__ __forceinline__ void gld16(const void* g, void* l){
    __builtin_amdgcn_global_load_lds(
        (const __attribute__((address_space(1))) unsigned int*)g,
        (__attribute__((address_space(3))) unsigned int*)l, 16, 0, 0);
}

// ---------------- W transpose + bf16 convert: Wt[n][k] = bf16(W[k][n]) ----------------
__global__ __launch_bounds__(256) void wtrans(
    const float* __restrict__ W0, const float* __restrict__ W1,
    const float* __restrict__ W2, const float* __restrict__ W3,
    unsigned short* __restrict__ T0, unsigned short* __restrict__ T1,
    unsigned short* __restrict__ T2, unsigned short* __restrict__ T3)
{
    __shared__ float tl[32][33];
    const float* W = blockIdx.z==0?W0: blockIdx.z==1?W1: blockIdx.z==2?W2:W3;
    unsigned short* T = blockIdx.z==0?T0: blockIdx.z==1?T1: blockIdx.z==2?T2:T3;
    const int t = threadIdx.x;
    const int bk = blockIdx.x*32, bn = blockIdx.y*32;
    {
        int row = t>>3, c4 = (t&7)*4;
        float4 v = *(const float4*)&W[(size_t)(bk+row)*D_ + bn + c4];
        tl[row][c4+0]=v.x; tl[row][c4+1]=v.y; tl[row][c4+2]=v.z; tl[row][c4+3]=v.w;
    }
    __syncthreads();
    {
        int n = t>>3, k4 = (t&7)*4;
        unsigned a = cvtpk(tl[k4+0][n], tl[k4+1][n]);
        unsigned b = cvtpk(tl[k4+2][n], tl[k4+3][n]);
        u32x2 pk = {a, b};
        *(u32x2*)&T[(size_t)(bn+n)*D_ + bk + k4] = pk;
    }
}

// ---------------- z-merged QKV projection GEMM (128^2 dbuf) + fused K pools ----------------
// Grid (32, 8, 3): blockIdx.x = ROW panel (XCD-pins A), blockIdx.y = col panel.
__global__ __launch_bounds__(256) void gemm_qkv3(
    const float* __restrict__ Aq, const float* __restrict__ Ak, const float* __restrict__ Avv,
    const unsigned short* __restrict__ Wq_, const unsigned short* __restrict__ Wk_,
    const unsigned short* __restrict__ Wv_,
    const float* __restrict__ bq_, const float* __restrict__ bk_, const float* __restrict__ bv_,
    unsigned short* __restrict__ Oq, unsigned short* __restrict__ Ok,
    unsigned short* __restrict__ Ov,
    unsigned short* __restrict__ K1, unsigned short* __restrict__ K2,
    float scale_q)
{
    const int z = blockIdx.z;
    const float* Af = z==0?Aq : z==1?Ak : Avv;
    const unsigned short* Btw = z==0?Wq_ : z==1?Wk_ : Wv_;
    const float* bias = z==0?bq_ : z==1?bk_ : bv_;
    unsigned short* C = z==0?Oq : z==1?Ok : Ov;
    const float scale = z==0? scale_q : 1.0f;

    const int N_ = D_, K_ = D_;
    __shared__ __align__(16) char lds[65536];    // dbuf: [cur][A 16K | B 16K]
    const int t = threadIdx.x;
    const int l = t & 63, wvi = t>>6, g = l>>4, x = l&15;
    const int wr = wvi>>1, wc = wvi&1;
    const int br = blockIdx.x*128, bc = blockIdx.y*128;   // TRANSPOSED grid

    int rw[4], bl[4];
    #pragma unroll
    for (int p=0;p<4;++p){ int u = t + 256*p; rw[p] = u>>3; bl[p] = u&7; }

    f4v acc[4][4];
    #pragma unroll
    for (int i=0;i<4;++i)
        #pragma unroll
        for (int j=0;j<4;++j) acc[i][j] = (f4v){0.f,0.f,0.f,0.f};

    float4 alo[4], ahi[4]; s8v brg[4];
    #pragma unroll
    for (int p=0;p<4;++p){
        const float* ap = Af + (size_t)(br+rw[p])*K_ + bl[p]*8;
        alo[p] = *(const float4*)ap; ahi[p] = *(const float4*)(ap+4);
        brg[p] = *(const s8v*)(Btw + (size_t)(bc+rw[p])*K_ + bl[p]*8);
    }

    int cur = 0;
    for (int kt=0; kt<K_; kt+=64){
        char* AsB = lds + cur*32768;
        char* BsB = AsB + 16384;
        #pragma unroll
        for (int p=0;p<4;++p){
            uint4 pk;
            pk.x = cvtpk(alo[p].x, alo[p].y); pk.y = cvtpk(alo[p].z, alo[p].w);
            pk.z = cvtpk(ahi[p].x, ahi[p].y); pk.w = cvtpk(ahi[p].z, ahi[p].w);
            *(uint4*)(AsB + swz(rw[p], bl[p])) = pk;
            *(s8v*)(BsB + swz(rw[p], bl[p])) = brg[p];
        }
        if (kt + 64 < K_){
            #pragma unroll
            for (int p=0;p<4;++p){
                const float* ap = Af + (size_t)(br+rw[p])*K_ + (kt+64) + bl[p]*8;
                alo[p] = *(const float4*)ap; ahi[p] = *(const float4*)(ap+4);
                brg[p] = *(const s8v*)(Btw + (size_t)(bc+rw[p])*K_ + (kt+64) + bl[p]*8);
            }
        }
        __syncthreads();
        #pragma unroll
        for (int c=0;c<2;++c){
            s8v af[4], bf[4];
            #pragma unroll
            for (int fm=0; fm<4; ++fm)
                af[fm] = *(const s8v*)(AsB + swz(wr*64+fm*16+x, c*4+g));
            #pragma unroll
            for (int fn=0; fn<4; ++fn)
                bf[fn] = *(const s8v*)(BsB + swz(wc*64+fn*16+x, c*4+g));
            __builtin_amdgcn_s_setprio(1);
            #pragma unroll
            for (int fm=0; fm<4; ++fm)
                #pragma unroll
                for (int fn=0; fn<4; ++fn)
                    acc[fm][fn] = __builtin_amdgcn_mfma_f32_16x16x32_bf16(
                        af[fm], bf[fn], acc[fm][fn], 0,0,0);
            __builtin_amdgcn_s_setprio(0);
        }
        cur ^= 1;
    }

    #pragma unroll
    for (int fn=0; fn<4; ++fn){
        int col = bc + wc*64 + fn*16 + x;
        float bv = bias[col];
        #pragma unroll
        for (int fm=0; fm<4; ++fm){
            int row0 = br + wr*64 + fm*16 + g*4;
            float v0 = acc[fm][fn][0] + bv;
            float v1 = acc[fm][fn][1] + bv;
            float v2 = acc[fm][fn][2] + bv;
            float v3 = acc[fm][fn][3] + bv;
            int bI = row0>>11, sI = row0 & (S_-1);
            int hI = col>>6,  dhI = col & (DH_-1);
            size_t bh = (size_t)(bI*H_ + hI);
            if (z != 2){
                unsigned short* p0 = C + (bh*S_ + sI)*DH_ + dhI;
                p0[0]      = f2bf1(v0*scale);
                p0[DH_]    = f2bf1(v1*scale);
                p0[2*DH_]  = f2bf1(v2*scale);
                p0[3*DH_]  = f2bf1(v3*scale);
                if (z == 1){   // fused K pools (coalesced 32B segments, exact algebra)
                    unsigned short* p1 = K1 + (bh*(S_/2) + (sI>>1))*DH_ + dhI;
                    p1[0]   = f2bf1((v0+v1)*0.5f);
                    p1[DH_] = f2bf1((v2+v3)*0.5f);
                    K2[(bh*(S_/4) + (sI>>2))*DH_ + dhI] = f2bf1((v0+v1+v2+v3)*0.25f);
                }
            } else {   // V: [B,H,DH,S], 4 consecutive tokens -> 8B store
                u32x2 pk;
                pk.x = cvtpk(v0, v1);
                pk.y = cvtpk(v2, v3);
                *(u32x2*)&C[(bh*DH_+dhI)*S_ + sI] = pk;
            }
        }
    }
}

// ---------------- V pools (both levels) from V0 [BH*DH][S]: fully coalesced ----------------
__global__ __launch_bounds__(256) void pool_v(
    const unsigned short* __restrict__ V0, unsigned short* __restrict__ V1,
    unsigned short* __restrict__ V2)
{
    int idx = blockIdx.x * 256 + threadIdx.x;       // 0 .. BH*DH*S/8-1
    int row = idx >> 8;                             // S/8 = 256 chunks per row
    int c8  = idx & 255;
    union { u32x4 u; unsigned short hh[8]; } a;
    a.u = *(const u32x4*)&V0[((size_t)row << 11) + c8*8];
    float m01 = 0.5f*(bf2f(a.hh[0])+bf2f(a.hh[1]));
    float m23 = 0.5f*(bf2f(a.hh[2])+bf2f(a.hh[3]));
    float m45 = 0.5f*(bf2f(a.hh[4])+bf2f(a.hh[5]));
    float m67 = 0.5f*(bf2f(a.hh[6])+bf2f(a.hh[7]));
    u32x2 p1; p1.x = cvtpk(m01, m23); p1.y = cvtpk(m45, m67);
    *(u32x2*)&V1[((size_t)row << 10) + c8*4] = p1;
    *(unsigned*)&V2[((size_t)row << 9) + c8*2] =
        cvtpk(0.5f*(m01+m23), 0.5f*(m45+m67));
}

// ---------------- final GEMM BM=128,BN=64: out = (a0+a1+a2)_bf16 @ Wto^T + bias ----------------
// Grid (32, 16): blockIdx.x = ROW panel (XCD-pins A), blockIdx.y = col panel.
__global__ __launch_bounds__(256) void gemm_sum(
    const unsigned short* __restrict__ A0, const unsigned short* __restrict__ A1,
    const unsigned short* __restrict__ A2, const unsigned short* __restrict__ Btw,
    const float* __restrict__ bias, float* __restrict__ C)
{
    const int N_ = D_, K_ = D_;
    __shared__ __align__(16) char lds[49152];   // dbuf: [cur][A 16K | B 8K]
    const int t = threadIdx.x;
    const int l = t & 63, wvi = t>>6, g = l>>4, x = l&15;
    const int wr = wvi>>1, wc = wvi&1;
    const int br = blockIdx.x*128, bc = blockIdx.y*64;    // TRANSPOSED grid

    int rw[4], bl[4];
    #pragma unroll
    for (int p=0;p<4;++p){ int u = t + 256*p; rw[p] = u>>3; bl[p] = u&7; }
    int bw[2], bb[2];
    #pragma unroll
    for (int p=0;p<2;++p){ int u = t + 256*p; bw[p] = u>>3; bb[p] = u&7; }

    f4v acc[4][2];
    #pragma unroll
    for (int i=0;i<4;++i){ acc[i][0] = (f4v){0,0,0,0}; acc[i][1] = (f4v){0,0,0,0}; }

    u32x4 a0r[4], a1r[4], a2r[4]; s8v brg[2];
    #pragma unroll
    for (int p=0;p<4;++p){
        size_t off = (size_t)(br+rw[p])*K_ + bl[p]*8;
        a0r[p] = *(const u32x4*)(A0 + off);
        a1r[p] = *(const u32x4*)(A1 + off);
        a2r[p] = *(const u32x4*)(A2 + off);
    }
    #pragma unroll
    for (int p=0;p<2;++p)
        brg[p] = *(const s8v*)(Btw + (size_t)(bc+bw[p])*K_ + bb[p]*8);

    int cur = 0;
    for (int kt=0; kt<K_; kt+=64){
        char* AsB = lds + cur*24576;
        char* BsB = AsB + 16384;
        #pragma unroll
        for (int p=0;p<4;++p){
            uint4 pk;
            pk.x = addpk3(a0r[p].x, a1r[p].x, a2r[p].x);
            pk.y = addpk3(a0r[p].y, a1r[p].y, a2r[p].y);
            pk.z = addpk3(a0r[p].z, a1r[p].z, a2r[p].z);
            pk.w = addpk3(a0r[p].w, a1r[p].w, a2r[p].w);
            *(uint4*)(AsB + swz(rw[p], bl[p])) = pk;
        }
        #pragma unroll
        for (int p=0;p<2;++p)
            *(s8v*)(BsB + swz(bw[p], bb[p])) = brg[p];
        if (kt + 64 < K_){
            #pragma unroll
            for (int p=0;p<4;++p){
                size_t off = (size_t)(br+rw[p])*K_ + (kt+64) + bl[p]*8;
                a0r[p] = *(const u32x4*)(A0 + off);
                a1r[p] = *(const u32x4*)(A1 + off);
                a2r[p] = *(const u32x4*)(A2 + off);
            }
            #pragma unroll
            for (int p=0;p<2;++p)
                brg[p] = *(const s8v*)(Btw + (size_t)(bc+bw[p])*K_ + (kt+64) + bb[p]*8);
        }
        __syncthreads();
        #pragma unroll
        for (int c=0;c<2;++c){
            s8v af[4], bf[2];
            #pragma unroll
            for (int fm=0; fm<4; ++fm)
                af[fm] = *(const s8v*)(AsB + swz(wr*64+fm*16+x, c*4+g));
            #pragma unroll
            for (int fn=0; fn<2; ++fn)
                bf[fn] = *(const s8v*)(BsB + swz(wc*32+fn*16+x, c*4+g));
            __builtin_amdgcn_s_setprio(1);
            #pragma unroll
            for (int fm=0; fm<4; ++fm)
                #pragma unroll
                for (int fn=0; fn<2; ++fn)
                    acc[fm][fn] = __builtin_amdgcn_mfma_f32_16x16x32_bf16(
                        af[fm], bf[fn], acc[fm][fn], 0,0,0);
            __builtin_amdgcn_s_setprio(0);
        }
        cur ^= 1;
    }

    #pragma unroll
    for (int fn=0; fn<2; ++fn){
        int col = bc + wc*32 + fn*16 + x;
        float bv = bias[col];
        #pragma unroll
        for (int fm=0; fm<4; ++fm){
            int row0 = br + wr*64 + fm*16 + g*4;
            #pragma unroll
            for (int r=0;r<4;++r)
                C[(size_t)(row0+r)*N_ + col] = acc[fm][fn][r] + bv;
        }
    }
}

// ---------------- MFMA flash attention: XCD-pinned heads + tree row-sum ----------------
__global__ __launch_bounds__(256, 4) void attn_mfma13(
    const unsigned short* __restrict__ qh,
    const unsigned short* __restrict__ kh0, const unsigned short* __restrict__ kh1,
    const unsigned short* __restrict__ kh2,
    const unsigned short* __restrict__ vt0, const unsigned short* __restrict__ vt1,
    const unsigned short* __restrict__ vt2,
    const float* __restrict__ wlv,
    unsigned short* __restrict__ acc0, unsigned short* __restrict__ acc1,
    unsigned short* __restrict__ acc2)
{
    __shared__ __align__(16) char ldsA[32768];   // [buf][ K 8KB | V 8KB ]
    const int t = threadIdx.x, l = t&63, wv = t>>6, q = l&31, hi = l>>5;
    const int bh_ = blockIdx.x;                  // b*H + h  (XCD = bh%8)
    const int h = bh_ & (H_-1), b = bh_ >> 4;
    const int qt = blockIdx.y;
    const int lvl = blockIdx.z;
    const int nt = 32 >> lvl;
    const unsigned short* kp  = lvl==0 ? kh0 : (lvl==1 ? kh1 : kh2);
    const unsigned short* vpt = lvl==0 ? vt0 : (lvl==1 ? vt1 : vt2);
    unsigned short* accOut    = lvl==0 ? acc0 : (lvl==1 ? acc1 : acc2);

    const float w0 = wlv[0], w1 = wlv[1], w2 = wlv[2];
    const float wl = wlv[lvl] / (w0 + w1 + w2);

    const unsigned short* qp =
        qh + (((size_t)(b*H_+h))*S_ + (size_t)qt*128 + wv*32 + q)*DH_ + hi*8;
    s8v qf0 = *(const s8v*)(qp);
    s8v qf1 = *(const s8v*)(qp + 16);
    s8v qf2 = *(const s8v*)(qp + 32);
    s8v qf3 = *(const s8v*)(qp + 48);

    const int Sl = nt*64;
    const char* gK = (const char*)(kp + (size_t)(b*H_+h)*Sl*DH_);
    const char* gV = (const char*)(vpt + (size_t)(b*H_+h)*DH_*Sl);

    // per-lane inverse-swizzled source offsets (chunk bases R0=wv*8, R1=32+wv*8)
    const int lr = l>>3, lc = l&7;
    const int kb0 = lc ^ lr ^ wv;          // (R0>>3)&7 == wv
    const int kb1 = lc ^ lr ^ (wv+4);      // (R1>>3)&7 == wv+4
    const int kOffG0 = (((wv*8+lr)*DH_)    + kb0*8)*2;
    const int kOffG1 = (((32+wv*8+lr)*DH_) + kb1*8)*2;
    const int vOffG0 = ((wv*8+lr)*Sl    + kb0*8)*2;
    const int vOffG1 = ((32+wv*8+lr)*Sl + kb1*8)*2;
    const int ldsOff0 = wv*1024, ldsOff1 = 4096 + wv*1024;

    float m_i = -1e30f, l_i = 0.f;
    f16v o0, o1;
    #pragma unroll
    for (int r=0;r<16;++r){ o0[r]=0.f; o1[r]=0.f; }

    // prologue: stage tile 0 into buf 0
    {
        char* kB = ldsA;           char* vB = ldsA + 8192;
        gld16(gK + kOffG0, kB + ldsOff0);
        gld16(gK + kOffG1, kB + ldsOff1);
        gld16(gV + vOffG0, vB + ldsOff0);
        gld16(gV + vOffG1, vB + ldsOff1);
    }

    int cur = 0;
    for (int kt = 0; kt < nt; ++kt) {
        asm volatile("s_waitcnt vmcnt(0)" ::: "memory");
        __syncthreads();                       // tile kt fully landed, prev reads done
        if (kt + 1 < nt) {                     // T14: next tile flies under compute
            char* kB = ldsA + (cur^1)*16384;
            char* vB = kB + 8192;
            gld16(gK + (size_t)(kt+1)*64*DH_*2 + kOffG0, kB + ldsOff0);
            gld16(gK + (size_t)(kt+1)*64*DH_*2 + kOffG1, kB + ldsOff1);
            gld16(gV + (size_t)(kt+1)*128      + vOffG0, vB + ldsOff0);
            gld16(gV + (size_t)(kt+1)*128      + vOffG1, vB + ldsOff1);
        }
        char* kb_ = ldsA + cur*16384;
        char* vb_ = kb_ + 8192;

        // ---- S^T = K @ Q^T (base-2 scaled), 2 sub-phases (4 K-frags live) ----
        f16v s0, s1;
        #pragma unroll
        for (int r=0;r<16;++r){ s0[r]=0.f; s1[r]=0.f; }
        {
            s8v k00 = *(const s8v*)(kb_ + swz(q,    0*2+hi));
            s8v k01 = *(const s8v*)(kb_ + swz(q,    1*2+hi));
            s8v k10 = *(const s8v*)(kb_ + swz(32+q, 0*2+hi));
            s8v k11 = *(const s8v*)(kb_ + swz(32+q, 1*2+hi));
            __builtin_amdgcn_s_setprio(1);
            s0 = __builtin_amdgcn_mfma_f32_32x32x16_bf16(k00, qf0, s0, 0,0,0);
            s1 = __builtin_amdgcn_mfma_f32_32x32x16_bf16(k10, qf0, s1, 0,0,0);
            s0 = __builtin_amdgcn_mfma_f32_32x32x16_bf16(k01, qf1, s0, 0,0,0);
            s1 = __builtin_amdgcn_mfma_f32_32x32x16_bf16(k11, qf1, s1, 0,0,0);
            __builtin_amdgcn_s_setprio(0);
        }
        {
            s8v k02 = *(const s8v*)(kb_ + swz(q,    2*2+hi));
            s8v k03 = *(const s8v*)(kb_ + swz(q,    3*2+hi));
            s8v k12 = *(const s8v*)(kb_ + swz(32+q, 2*2+hi));
            s8v k13 = *(const s8v*)(kb_ + swz(32+q, 3*2+hi));
            __builtin_amdgcn_s_setprio(1);
            s0 = __builtin_amdgcn_mfma_f32_32x32x16_bf16(k02, qf2, s0, 0,0,0);
            s1 = __builtin_amdgcn_mfma_f32_32x32x16_bf16(k12, qf2, s1, 0,0,0);
            s0 = __builtin_amdgcn_mfma_f32_32x32x16_bf16(k03, qf3, s0, 0,0,0);
            s1 = __builtin_amdgcn_mfma_f32_32x32x16_bf16(k13, qf3, s1, 0,0,0);
            __builtin_amdgcn_s_setprio(0);
        }

        // ---- row max (4 parallel max3 chains) ----
        float ca = max3_(s0[0], s0[1], s0[2]);
        ca = max3_(ca, s0[3], s0[4]);
        ca = max3_(ca, s0[5], s0[6]);
        ca = fmaxf(ca, s0[7]);
        float cb = max3_(s0[8], s0[9], s0[10]);
        cb = max3_(cb, s0[11], s0[12]);
        cb = max3_(cb, s0[13], s0[14]);
        cb = fmaxf(cb, s0[15]);
        float cc = max3_(s1[0], s1[1], s1[2]);
        cc = max3_(cc, s1[3], s1[4]);
        cc = max3_(cc, s1[5], s1[6]);
        cc = fmaxf(cc, s1[7]);
        float cd = max3_(s1[8], s1[9], s1[10]);
        cd = max3_(cd, s1[11], s1[12]);
        cd = max3_(cd, s1[13], s1[14]);
        cd = fmaxf(cd, s1[15]);
        float pm = fmaxf(max3_(ca, cb, cc), cd);
        pm = fmaxf(pm, __shfl_xor(pm, 32, 64));
        if (__any(pm > m_i + THR2)) {
            float mn = fmaxf(m_i, pm);
            float corr = exp2_(m_i - mn);
            m_i = mn;
            l_i *= corr;
            #pragma unroll
            for (int r=0;r<16;++r){
                float cbc = __shfl(corr, ((r&3)+8*(r>>2)) + 4*hi, 64);
                o0[r] *= cbc; o1[r] *= cbc;
            }
        }

        // ---- exponentiate + tree row-sum ----
        #pragma unroll
        for (int r=0;r<16;++r) s0[r] = exp2_(s0[r]-m_i);
        #pragma unroll
        for (int r=0;r<16;++r) s1[r] = exp2_(s1[r]-m_i);
        {
            float r0 = s0[0]+s0[4],  r1 = s0[1]+s0[5];
            float r2 = s0[2]+s0[6],  r3 = s0[3]+s0[7];
            float r4 = s1[0]+s1[4],  r5 = s1[1]+s1[5];
            float r6 = s1[2]+s1[6],  r7 = s1[3]+s1[7];
            r0 += s0[8]+s0[12];  r1 += s0[9]+s0[13];
            r2 += s0[10]+s0[14]; r3 += s0[11]+s0[15];
            r4 += s1[8]+s1[12];  r5 += s1[9]+s1[13];
            r6 += s1[10]+s1[14]; r7 += s1[11]+s1[15];
            float rs = ((r0+r1)+(r2+r3)) + ((r4+r5)+(r6+r7));
            rs += __shfl_xor(rs, 32, 64);
            l_i += rs;
        }

        // ---- P-frags in-register: cvt_pk pairs + permlane32_swap ----
        unsigned a0 = cvtpk(s0[0], s0[1]),  a1 = cvtpk(s0[2], s0[3]);
        unsigned b0 = cvtpk(s0[4], s0[5]),  b1 = cvtpk(s0[6], s0[7]);
        pswap(a0, b0); pswap(a1, b1);
        unsigned c0 = cvtpk(s0[8], s0[9]),  c1 = cvtpk(s0[10], s0[11]);
        unsigned d0 = cvtpk(s0[12], s0[13]),d1 = cvtpk(s0[14], s0[15]);
        pswap(c0, d0); pswap(c1, d1);
        unsigned e0 = cvtpk(s1[0], s1[1]),  e1 = cvtpk(s1[2], s1[3]);
        unsigned f0 = cvtpk(s1[4], s1[5]),  f1 = cvtpk(s1[6], s1[7]);
        pswap(e0, f0); pswap(e1, f1);
        unsigned g0 = cvtpk(s1[8], s1[9]),  g1 = cvtpk(s1[10], s1[11]);
        unsigned h0 = cvtpk(s1[12], s1[13]),h1 = cvtpk(s1[14], s1[15]);
        pswap(g0, h0); pswap(g1, h1);
        union { u32x4 u; s8v s; } pf0, pf1, pf2, pf3;
        pf0.u = (u32x4){a0, a1, b0, b1};
        pf1.u = (u32x4){c0, c1, d0, d1};
        pf2.u = (u32x4){e0, e1, f0, f1};
        pf3.u = (u32x4){g0, g1, h0, h1};

        // ---- O += P @ V, 2 sub-phases (4 V-frags live) ----
        {
            s8v v00 = *(const s8v*)(vb_ + swz(q,    0*2+hi));
            s8v v01 = *(const s8v*)(vb_ + swz(q,    1*2+hi));
            s8v v10 = *(const s8v*)(vb_ + swz(32+q, 0*2+hi));
            s8v v11 = *(const s8v*)(vb_ + swz(32+q, 1*2+hi));
            __builtin_amdgcn_s_setprio(1);
            o0 = __builtin_amdgcn_mfma_f32_32x32x16_bf16(pf0.s, v00, o0, 0,0,0);
            o1 = __builtin_amdgcn_mfma_f32_32x32x16_bf16(pf0.s, v10, o1, 0,0,0);
            o0 = __builtin_amdgcn_mfma_f32_32x32x16_bf16(pf1.s, v01, o0, 0,0,0);
            o1 = __builtin_amdgcn_mfma_f32_32x32x16_bf16(pf1.s, v11, o1, 0,0,0);
            __builtin_amdgcn_s_setprio(0);
        }
        {
            s8v v02 = *(const s8v*)(vb_ + swz(q,    2*2+hi));
            s8v v03 = *(const s8v*)(vb_ + swz(q,    3*2+hi));
            s8v v12 = *(const s8v*)(vb_ + swz(32+q, 2*2+hi));
            s8v v13 = *(const s8v*)(vb_ + swz(32+q, 3*2+hi));
            __builtin_amdgcn_s_setprio(1);
            o0 = __builtin_amdgcn_mfma_f32_32x32x16_bf16(pf2.s, v02, o0, 0,0,0);
            o1 = __builtin_amdgcn_mfma_f32_32x32x16_bf16(pf2.s, v12, o1, 0,0,0);
            o0 = __builtin_amdgcn_mfma_f32_32x32x16_bf16(pf3.s, v03, o0, 0,0,0);
            o1 = __builtin_amdgcn_mfma_f32_32x32x16_bf16(pf3.s, v13, o1, 0,0,0);
            __builtin_amdgcn_s_setprio(0);
        }
        cur ^= 1;
    }

    #pragma unroll
    for (int r=0;r<16;++r){
        int qrow = ((r&3)+8*(r>>2)) + 4*hi;
        float lb = __shfl(l_i, qrow, 64);
        float sc = wl / lb;
        size_t row = (size_t)b*S_ + (size_t)qt*128 + wv*32 + qrow;
        accOut[row*D_ + h*DH_ + q]      = f2bf1(o0[r] * sc);
        accOut[row*D_ + h*DH_ + 32 + q] = f2bf1(o1[r] * sc);
    }
}

// ---------------- launch ----------------
extern "C" void kernel_launch(void* const* d_in, const int* in_sizes, int n_in,
                              void* d_out, int out_size, void* d_ws, size_t ws_size,
                              hipStream_t stream)
{
    const float* query = (const float*)d_in[0];
    const float* key   = (const float*)d_in[1];
    const float* value = (const float*)d_in[2];
    const float* Wq = (const float*)d_in[3];  const float* bq = (const float*)d_in[4];
    const float* Wk = (const float*)d_in[5];  const float* bk = (const float*)d_in[6];
    const float* Wv = (const float*)d_in[7];  const float* bv = (const float*)d_in[8];
    const float* Wo = (const float*)d_in[9];  const float* bo = (const float*)d_in[10];
    const float* wlv = (const float*)d_in[11];

    char* w = (char*)d_ws;
    unsigned short* qhb  = (unsigned short*)(w);             // 8 MB [B,H,S,DH]
    unsigned short* khb0 = (unsigned short*)(w + 8388608);   // 8 MB [B,H,S,DH]
    unsigned short* khb1 = (unsigned short*)(w + 16777216);  // 4 MB
    unsigned short* khb2 = (unsigned short*)(w + 20971520);  // 2 MB
    unsigned short* vtb0 = (unsigned short*)(w + 23068672);  // 8 MB [B,H,DH,S]
    unsigned short* vtb1 = (unsigned short*)(w + 31457280);  // 4 MB
    unsigned short* vtb2 = (unsigned short*)(w + 35651584);  // 2 MB
    unsigned short* Wto  = (unsigned short*)(w + 37748736);  // 2 MB
    unsigned short* Wtq  = (unsigned short*)(w + 39845888);  // 2 MB (dead after proj)
    unsigned short* Wtk  = (unsigned short*)(w + 41943040);  // 2 MB (dead after proj)
    unsigned short* Wtv  = (unsigned short*)(w + 44040192);  // 2 MB (dead after proj)
    unsigned short* acc0 = (unsigned short*)(w + 39845888);  // 8 MB, overlaps Wtq..Wtv
    unsigned short* acc1 = (unsigned short*)(w + 48234496);  // 8 MB
    unsigned short* acc2 = (unsigned short*)(w + 56623104);  // 8 MB -> end 65,011,712

    dim3 bb(256);
    wtrans<<<dim3(32,32,4), bb, 0, stream>>>(Wq, Wk, Wv, Wo, Wtq, Wtk, Wtv, Wto);

    const float scale_q = 0.125f * 1.44269504088896f;   // 1/sqrt(DH) * log2(e)
    gemm_qkv3<<<dim3(32, 8, 3), bb, 0, stream>>>(query, key, value,
                                                 Wtq, Wtk, Wtv, bq, bk, bv,
                                                 qhb, khb0, vtb0,
                                                 khb1, khb2, scale_q);

    // V pools: BH*DH*S/8 threads = 524288 -> 2048 blocks, fully coalesced
    pool_v<<<2048, bb, 0, stream>>>(vtb0, vtb1, vtb2);

    attn_mfma13<<<dim3(32, 16, 3), bb, 0, stream>>>(qhb, khb0, khb1, khb2,
                                                    vtb0, vtb1, vtb2, wlv,
                                                    acc0, acc1, acc2);

    gemm_sum<<<dim3(32, 16), bb, 0, stream>>>(acc0, acc1, acc2, Wto, bo, (float*)d_out);
}

// Round 25
// 162.593 us; speedup vs baseline: 1.0880x; 1.0003x over previous
//
#include <hip/hip_runtime.h>

// Hierarchical 3-level pooled MHA. FINAL (= R20/R22/R24, 162.6-163.0 us,
// reproduced 3x). Design point: bf16 MFMA everywhere; z-merged XCD-pinned
// projection GEMM with fused K-pools; coalesced V-pool kernel; one-level-per-
// block XCD-pinned flash attention (64 VGPR, 3 waves/SIMD, liveness-minimal
// order, gld16 dbuf staging, exp2 defer-max softmax, in-register P via
// cvt_pk+permlane32_swap); 3-way partial-sum final GEMM.
// B=2, S=2048, D=1024, H=16, DH=64.

#define B_  2
#define S_  2048
#define D_  1024
#define H_  16
#define DH_ 64
#define THR2 10.0f   // defer-max threshold, base-2 domain

typedef short s8v __attribute__((ext_vector_type(8)));    // 8 bf16
typedef float f4v __attribute__((ext_vector_type(4)));
typedef float f16v __attribute__((ext_vector_type(16)));  // 32x32 accum
typedef unsigned int u32x2 __attribute__((ext_vector_type(2)));
typedef unsigned int u32x4 __attribute__((ext_vector_type(4)));

__device__ __forceinline__ unsigned cvtpk(float lo, float hi){
    unsigned r;
    asm volatile("v_cvt_pk_bf16_f32 %0, %1, %2" : "=v"(r) : "v"(lo), "v"(hi));
    return r;
}
__device__ __forceinline__ unsigned short f2bf1(float v){
    unsigned r;
    asm volatile("v_cvt_pk_bf16_f32 %0, %1, %2" : "=v"(r) : "v"(v), "v"(v));
    return (unsigned short)r;
}
__device__ __forceinline__ float bf2f(unsigned short h){
    union { unsigned u; float f; } v; v.u = ((unsigned)h) << 16;
    return v.f;
}
__device__ __forceinline__ float exp2_(float x){
    float r; asm("v_exp_f32 %0, %1" : "=v"(r) : "v"(x)); return r;
}
__device__ __forceinline__ float max3_(float a, float b, float c){
    float r; asm("v_max3_f32 %0, %1, %2, %3" : "=v"(r) : "v"(a), "v"(b), "v"(c));
    return r;
}
// v_permlane32_swap_b32 vdst, vsrc: vdst[32:63] <-> vsrc[0:31] (both updated).
__device__ __forceinline__ void pswap(unsigned &dst, unsigned &src){
    asm volatile("v_permlane32_swap_b32 %0, %1" : "+v"(dst), "+v"(src));
}
// three bf16x2 -> bf16x2 sum, single RNE repack (f32 adds)
__device__ __forceinline__ unsigned addpk3(unsigned x, unsigned y, unsigned z){
    union { unsigned u; float f; } xl, yl, zl, xh, yh, zh;
    xl.u = x << 16;          yl.u = y << 16;          zl.u = z << 16;
    xh.u = x & 0xFFFF0000u;  yh.u = y & 0xFFFF0000u;  zh.u = z & 0xFFFF0000u;
    return cvtpk(xl.f + yl.f + zl.f, xh.f + yh.f + zh.f);
}
// XOR-swizzled byte offset of 16B block kb in row `row` of a [rows][64bf16] tile.
__device__ __forceinline__ int swz(int row, int kb){
    return row*128 + (((kb) ^ (row & 7) ^ ((row >> 3) & 7)) << 4);
}
// async 16B global->LDS; LDS dest = wave-uniform base + lane*16 (linear)
__device__ __forceinline__ void gld16(const void* g, void* l){
    __builtin_amdgcn_global_load_lds(
        (const __attribute__((address_space(1))) unsigned int*)g,
        (__attribute__((address_space(3))) unsigned int*)l, 16, 0, 0);
}

// ---------------- W transpose + bf16 convert: Wt[n][k] = bf16(W[k][n]) ----------------
__global__ __launch_bounds__(256) void wtrans(
    const float* __restrict__ W0, const float* __restrict__ W1,
    const float* __restrict__ W2, const float* __restrict__ W3,
    unsigned short* __restrict__ T0, unsigned short* __restrict__ T1,
    unsigned short* __restrict__ T2, unsigned short* __restrict__ T3)
{
    __shared__ float tl[32][33];
    const float* W = blockIdx.z==0?W0: blockIdx.z==1?W1: blockIdx.z==2?W2:W3;
    unsigned short* T = blockIdx.z==0?T0: blockIdx.z==1?T1: blockIdx.z==2?T2:T3;
    const int t = threadIdx.x;
    const int bk = blockIdx.x*32, bn = blockIdx.y*32;
    {
        int row = t>>3, c4 = (t&7)*4;
        float4 v = *(const float4*)&W[(size_t)(bk+row)*D_ + bn + c4];
        tl[row][c4+0]=v.x; tl[row][c4+1]=v.y; tl[row][c4+2]=v.z; tl[row][c4+3]=v.w;
    }
    __syncthreads();
    {
        int n = t>>3, k4 = (t&7)*4;
        unsigned a = cvtpk(tl[k4+0][n], tl[k4+1][n]);
        unsigned b = cvtpk(tl[k4+2][n], tl[k4+3][n]);
        u32x2 pk = {a, b};
        *(u32x2*)&T[(size_t)(bn+n)*D_ + bk + k4] = pk;
    }
}

// ---------------- z-merged QKV projection GEMM (128^2 dbuf) + fused K pools ----------------
// Grid (32, 8, 3): blockIdx.x = ROW panel (XCD-pins A), blockIdx.y = col panel.
__global__ __launch_bounds__(256) void gemm_qkv3(
    const float* __restrict__ Aq, const float* __restrict__ Ak, const float* __restrict__ Avv,
    const unsigned short* __restrict__ Wq_, const unsigned short* __restrict__ Wk_,
    const unsigned short* __restrict__ Wv_,
    const float* __restrict__ bq_, const float* __restrict__ bk_, const float* __restrict__ bv_,
    unsigned short* __restrict__ Oq, unsigned short* __restrict__ Ok,
    unsigned short* __restrict__ Ov,
    unsigned short* __restrict__ K1, unsigned short* __restrict__ K2,
    float scale_q)
{
    const int z = blockIdx.z;
    const float* Af = z==0?Aq : z==1?Ak : Avv;
    const unsigned short* Btw = z==0?Wq_ : z==1?Wk_ : Wv_;
    const float* bias = z==0?bq_ : z==1?bk_ : bv_;
    unsigned short* C = z==0?Oq : z==1?Ok : Ov;
    const float scale = z==0? scale_q : 1.0f;

    const int N_ = D_, K_ = D_;
    __shared__ __align__(16) char lds[65536];    // dbuf: [cur][A 16K | B 16K]
    const int t = threadIdx.x;
    const int l = t & 63, wvi = t>>6, g = l>>4, x = l&15;
    const int wr = wvi>>1, wc = wvi&1;
    const int br = blockIdx.x*128, bc = blockIdx.y*128;   // TRANSPOSED grid

    int rw[4], bl[4];
    #pragma unroll
    for (int p=0;p<4;++p){ int u = t + 256*p; rw[p] = u>>3; bl[p] = u&7; }

    f4v acc[4][4];
    #pragma unroll
    for (int i=0;i<4;++i)
        #pragma unroll
        for (int j=0;j<4;++j) acc[i][j] = (f4v){0.f,0.f,0.f,0.f};

    float4 alo[4], ahi[4]; s8v brg[4];
    #pragma unroll
    for (int p=0;p<4;++p){
        const float* ap = Af + (size_t)(br+rw[p])*K_ + bl[p]*8;
        alo[p] = *(const float4*)ap; ahi[p] = *(const float4*)(ap+4);
        brg[p] = *(const s8v*)(Btw + (size_t)(bc+rw[p])*K_ + bl[p]*8);
    }

    int cur = 0;
    for (int kt=0; kt<K_; kt+=64){
        char* AsB = lds + cur*32768;
        char* BsB = AsB + 16384;
        #pragma unroll
        for (int p=0;p<4;++p){
            uint4 pk;
            pk.x = cvtpk(alo[p].x, alo[p].y); pk.y = cvtpk(alo[p].z, alo[p].w);
            pk.z = cvtpk(ahi[p].x, ahi[p].y); pk.w = cvtpk(ahi[p].z, ahi[p].w);
            *(uint4*)(AsB + swz(rw[p], bl[p])) = pk;
            *(s8v*)(BsB + swz(rw[p], bl[p])) = brg[p];
        }
        if (kt + 64 < K_){
            #pragma unroll
            for (int p=0;p<4;++p){
                const float* ap = Af + (size_t)(br+rw[p])*K_ + (kt+64) + bl[p]*8;
                alo[p] = *(const float4*)ap; ahi[p] = *(const float4*)(ap+4);
                brg[p] = *(const s8v*)(Btw + (size_t)(bc+rw[p])*K_ + (kt+64) + bl[p]*8);
            }
        }
        __syncthreads();
        #pragma unroll
        for (int c=0;c<2;++c){
            s8v af[4], bf[4];
            #pragma unroll
            for (int fm=0; fm<4; ++fm)
                af[fm] = *(const s8v*)(AsB + swz(wr*64+fm*16+x, c*4+g));
            #pragma unroll
            for (int fn=0; fn<4; ++fn)
                bf[fn] = *(const s8v*)(BsB + swz(wc*64+fn*16+x, c*4+g));
            __builtin_amdgcn_s_setprio(1);
            #pragma unroll
            for (int fm=0; fm<4; ++fm)
                #pragma unroll
                for (int fn=0; fn<4; ++fn)
                    acc[fm][fn] = __builtin_amdgcn_mfma_f32_16x16x32_bf16(
                        af[fm], bf[fn], acc[fm][fn], 0,0,0);
            __builtin_amdgcn_s_setprio(0);
        }
        cur ^= 1;
    }

    #pragma unroll
    for (int fn=0; fn<4; ++fn){
        int col = bc + wc*64 + fn*16 + x;
        float bv = bias[col];
        #pragma unroll
        for (int fm=0; fm<4; ++fm){
            int row0 = br + wr*64 + fm*16 + g*4;
            float v0 = acc[fm][fn][0] + bv;
            float v1 = acc[fm][fn][1] + bv;
            float v2 = acc[fm][fn][2] + bv;
            float v3 = acc[fm][fn][3] + bv;
            int bI = row0>>11, sI = row0 & (S_-1);
            int hI = col>>6,  dhI = col & (DH_-1);
            size_t bh = (size_t)(bI*H_ + hI);
            if (z != 2){
                unsigned short* p0 = C + (bh*S_ + sI)*DH_ + dhI;
                p0[0]      = f2bf1(v0*scale);
                p0[DH_]    = f2bf1(v1*scale);
                p0[2*DH_]  = f2bf1(v2*scale);
                p0[3*DH_]  = f2bf1(v3*scale);
                if (z == 1){   // fused K pools (coalesced 32B segments, exact algebra)
                    unsigned short* p1 = K1 + (bh*(S_/2) + (sI>>1))*DH_ + dhI;
                    p1[0]   = f2bf1((v0+v1)*0.5f);
                    p1[DH_] = f2bf1((v2+v3)*0.5f);
                    K2[(bh*(S_/4) + (sI>>2))*DH_ + dhI] = f2bf1((v0+v1+v2+v3)*0.25f);
                }
            } else {   // V: [B,H,DH,S], 4 consecutive tokens -> 8B store
                u32x2 pk;
                pk.x = cvtpk(v0, v1);
                pk.y = cvtpk(v2, v3);
                *(u32x2*)&C[(bh*DH_+dhI)*S_ + sI] = pk;
            }
        }
    }
}

// ---------------- V pools (both levels) from V0 [BH*DH][S]: fully coalesced ----------------
__global__ __launch_bounds__(256) void pool_v(
    const unsigned short* __restrict__ V0, unsigned short* __restrict__ V1,
    unsigned short* __restrict__ V2)
{
    int idx = blockIdx.x * 256 + threadIdx.x;       // 0 .. BH*DH*S/8-1
    int row = idx >> 8;                             // S/8 = 256 chunks per row
    int c8  = idx & 255;
    union { u32x4 u; unsigned short hh[8]; } a;
    a.u = *(const u32x4*)&V0[((size_t)row << 11) + c8*8];
    float m01 = 0.5f*(bf2f(a.hh[0])+bf2f(a.hh[1]));
    float m23 = 0.5f*(bf2f(a.hh[2])+bf2f(a.hh[3]));
    float m45 = 0.5f*(bf2f(a.hh[4])+bf2f(a.hh[5]));
    float m67 = 0.5f*(bf2f(a.hh[6])+bf2f(a.hh[7]));
    u32x2 p1; p1.x = cvtpk(m01, m23); p1.y = cvtpk(m45, m67);
    *(u32x2*)&V1[((size_t)row << 10) + c8*4] = p1;
    *(unsigned*)&V2[((size_t)row << 9) + c8*2] =
        cvtpk(0.5f*(m01+m23), 0.5f*(m45+m67));
}

// ---------------- final GEMM BM=128,BN=64: out = (a0+a1+a2)_bf16 @ Wto^T + bias ----------------
// Grid (32, 16): blockIdx.x = ROW panel (XCD-pins A), blockIdx.y = col panel.
__global__ __launch_bounds__(256) void gemm_sum(
    const unsigned short* __restrict__ A0, const unsigned short* __restrict__ A1,
    const unsigned short* __restrict__ A2, const unsigned short* __restrict__ Btw,
    const float* __restrict__ bias, float* __restrict__ C)
{
    const int N_ = D_, K_ = D_;
    __shared__ __align__(16) char lds[49152];   // dbuf: [cur][A 16K | B 8K]
    const int t = threadIdx.x;
    const int l = t & 63, wvi = t>>6, g = l>>4, x = l&15;
    const int wr = wvi>>1, wc = wvi&1;
    const int br = blockIdx.x*128, bc = blockIdx.y*64;    // TRANSPOSED grid

    int rw[4], bl[4];
    #pragma unroll
    for (int p=0;p<4;++p){ int u = t + 256*p; rw[p] = u>>3; bl[p] = u&7; }
    int bw[2], bb[2];
    #pragma unroll
    for (int p=0;p<2;++p){ int u = t + 256*p; bw[p] = u>>3; bb[p] = u&7; }

    f4v acc[4][2];
    #pragma unroll
    for (int i=0;i<4;++i){ acc[i][0] = (f4v){0,0,0,0}; acc[i][1] = (f4v){0,0,0,0}; }

    u32x4 a0r[4], a1r[4], a2r[4]; s8v brg[2];
    #pragma unroll
    for (int p=0;p<4;++p){
        size_t off = (size_t)(br+rw[p])*K_ + bl[p]*8;
        a0r[p] = *(const u32x4*)(A0 + off);
        a1r[p] = *(const u32x4*)(A1 + off);
        a2r[p] = *(const u32x4*)(A2 + off);
    }
    #pragma unroll
    for (int p=0;p<2;++p)
        brg[p] = *(const s8v*)(Btw + (size_t)(bc+bw[p])*K_ + bb[p]*8);

    int cur = 0;
    for (int kt=0; kt<K_; kt+=64){
        char* AsB = lds + cur*24576;
        char* BsB = AsB + 16384;
        #pragma unroll
        for (int p=0;p<4;++p){
            uint4 pk;
            pk.x = addpk3(a0r[p].x, a1r[p].x, a2r[p].x);
            pk.y = addpk3(a0r[p].y, a1r[p].y, a2r[p].y);
            pk.z = addpk3(a0r[p].z, a1r[p].z, a2r[p].z);
            pk.w = addpk3(a0r[p].w, a1r[p].w, a2r[p].w);
            *(uint4*)(AsB + swz(rw[p], bl[p])) = pk;
        }
        #pragma unroll
        for (int p=0;p<2;++p)
            *(s8v*)(BsB + swz(bw[p], bb[p])) = brg[p];
        if (kt + 64 < K_){
            #pragma unroll
            for (int p=0;p<4;++p){
                size_t off = (size_t)(br+rw[p])*K_ + (kt+64) + bl[p]*8;
                a0r[p] = *(const u32x4*)(A0 + off);
                a1r[p] = *(const u32x4*)(A1 + off);
                a2r[p] = *(const u32x4*)(A2 + off);
            }
            #pragma unroll
            for (int p=0;p<2;++p)
                brg[p] = *(const s8v*)(Btw + (size_t)(bc+bw[p])*K_ + (kt+64) + bb[p]*8);
        }
        __syncthreads();
        #pragma unroll
        for (int c=0;c<2;++c){
            s8v af[4], bf[2];
            #pragma unroll
            for (int fm=0; fm<4; ++fm)
                af[fm] = *(const s8v*)(AsB + swz(wr*64+fm*16+x, c*4+g));
            #pragma unroll
            for (int fn=0; fn<2; ++fn)
                bf[fn] = *(const s8v*)(BsB + swz(wc*32+fn*16+x, c*4+g));
            __builtin_amdgcn_s_setprio(1);
            #pragma unroll
            for (int fm=0; fm<4; ++fm)
                #pragma unroll
                for (int fn=0; fn<2; ++fn)
                    acc[fm][fn] = __builtin_amdgcn_mfma_f32_16x16x32_bf16(
                        af[fm], bf[fn], acc[fm][fn], 0,0,0);
            __builtin_amdgcn_s_setprio(0);
        }
        cur ^= 1;
    }

    #pragma unroll
    for (int fn=0; fn<2; ++fn){
        int col = bc + wc*32 + fn*16 + x;
        float bv = bias[col];
        #pragma unroll
        for (int fm=0; fm<4; ++fm){
            int row0 = br + wr*64 + fm*16 + g*4;
            #pragma unroll
            for (int r=0;r<4;++r)
                C[(size_t)(row0+r)*N_ + col] = acc[fm][fn][r] + bv;
        }
    }
}

// ---------------- MFMA flash attention: XCD-pinned heads + tree row-sum ----------------
__global__ __launch_bounds__(256, 4) void attn_mfma13(
    const unsigned short* __restrict__ qh,
    const unsigned short* __restrict__ kh0, const unsigned short* __restrict__ kh1,
    const unsigned short* __restrict__ kh2,
    const unsigned short* __restrict__ vt0, const unsigned short* __restrict__ vt1,
    const unsigned short* __restrict__ vt2,
    const float* __restrict__ wlv,
    unsigned short* __restrict__ acc0, unsigned short* __restrict__ acc1,
    unsigned short* __restrict__ acc2)
{
    __shared__ __align__(16) char ldsA[32768];   // [buf][ K 8KB | V 8KB ]
    const int t = threadIdx.x, l = t&63, wv = t>>6, q = l&31, hi = l>>5;
    const int bh_ = blockIdx.x;                  // b*H + h  (XCD = bh%8)
    const int h = bh_ & (H_-1), b = bh_ >> 4;
    const int qt = blockIdx.y;
    const int lvl = blockIdx.z;
    const int nt = 32 >> lvl;
    const unsigned short* kp  = lvl==0 ? kh0 : (lvl==1 ? kh1 : kh2);
    const unsigned short* vpt = lvl==0 ? vt0 : (lvl==1 ? vt1 : vt2);
    unsigned short* accOut    = lvl==0 ? acc0 : (lvl==1 ? acc1 : acc2);

    const float w0 = wlv[0], w1 = wlv[1], w2 = wlv[2];
    const float wl = wlv[lvl] / (w0 + w1 + w2);

    const unsigned short* qp =
        qh + (((size_t)(b*H_+h))*S_ + (size_t)qt*128 + wv*32 + q)*DH_ + hi*8;
    s8v qf0 = *(const s8v*)(qp);
    s8v qf1 = *(const s8v*)(qp + 16);
    s8v qf2 = *(const s8v*)(qp + 32);
    s8v qf3 = *(const s8v*)(qp + 48);

    const int Sl = nt*64;
    const char* gK = (const char*)(kp + (size_t)(b*H_+h)*Sl*DH_);
    const char* gV = (const char*)(vpt + (size_t)(b*H_+h)*DH_*Sl);

    // per-lane inverse-swizzled source offsets (chunk bases R0=wv*8, R1=32+wv*8)
    const int lr = l>>3, lc = l&7;
    const int kb0 = lc ^ lr ^ wv;          // (R0>>3)&7 == wv
    const int kb1 = lc ^ lr ^ (wv+4);      // (R1>>3)&7 == wv+4
    const int kOffG0 = (((wv*8+lr)*DH_)    + kb0*8)*2;
    const int kOffG1 = (((32+wv*8+lr)*DH_) + kb1*8)*2;
    const int vOffG0 = ((wv*8+lr)*Sl    + kb0*8)*2;
    const int vOffG1 = ((32+wv*8+lr)*Sl + kb1*8)*2;
    const int ldsOff0 = wv*1024, ldsOff1 = 4096 + wv*1024;

    float m_i = -1e30f, l_i = 0.f;
    f16v o0, o1;
    #pragma unroll
    for (int r=0;r<16;++r){ o0[r]=0.f; o1[r]=0.f; }

    // prologue: stage tile 0 into buf 0
    {
        char* kB = ldsA;           char* vB = ldsA + 8192;
        gld16(gK + kOffG0, kB + ldsOff0);
        gld16(gK + kOffG1, kB + ldsOff1);
        gld16(gV + vOffG0, vB + ldsOff0);
        gld16(gV + vOffG1, vB + ldsOff1);
    }

    int cur = 0;
    for (int kt = 0; kt < nt; ++kt) {
        asm volatile("s_waitcnt vmcnt(0)" ::: "memory");
        __syncthreads();                       // tile kt fully landed, prev reads done
        if (kt + 1 < nt) {                     // T14: next tile flies under compute
            char* kB = ldsA + (cur^1)*16384;
            char* vB = kB + 8192;
            gld16(gK + (size_t)(kt+1)*64*DH_*2 + kOffG0, kB + ldsOff0);
            gld16(gK + (size_t)(kt+1)*64*DH_*2 + kOffG1, kB + ldsOff1);
            gld16(gV + (size_t)(kt+1)*128      + vOffG0, vB + ldsOff0);
            gld16(gV + (size_t)(kt+1)*128      + vOffG1, vB + ldsOff1);
        }
        char* kb_ = ldsA + cur*16384;
        char* vb_ = kb_ + 8192;

        // ---- S^T = K @ Q^T (base-2 scaled), 2 sub-phases (4 K-frags live) ----
        f16v s0, s1;
        #pragma unroll
        for (int r=0;r<16;++r){ s0[r]=0.f; s1[r]=0.f; }
        {
            s8v k00 = *(const s8v*)(kb_ + swz(q,    0*2+hi));
            s8v k01 = *(const s8v*)(kb_ + swz(q,    1*2+hi));
            s8v k10 = *(const s8v*)(kb_ + swz(32+q, 0*2+hi));
            s8v k11 = *(const s8v*)(kb_ + swz(32+q, 1*2+hi));
            __builtin_amdgcn_s_setprio(1);
            s0 = __builtin_amdgcn_mfma_f32_32x32x16_bf16(k00, qf0, s0, 0,0,0);
            s1 = __builtin_amdgcn_mfma_f32_32x32x16_bf16(k10, qf0, s1, 0,0,0);
            s0 = __builtin_amdgcn_mfma_f32_32x32x16_bf16(k01, qf1, s0, 0,0,0);
            s1 = __builtin_amdgcn_mfma_f32_32x32x16_bf16(k11, qf1, s1, 0,0,0);
            __builtin_amdgcn_s_setprio(0);
        }
        {
            s8v k02 = *(const s8v*)(kb_ + swz(q,    2*2+hi));
            s8v k03 = *(const s8v*)(kb_ + swz(q,    3*2+hi));
            s8v k12 = *(const s8v*)(kb_ + swz(32+q, 2*2+hi));
            s8v k13 = *(const s8v*)(kb_ + swz(32+q, 3*2+hi));
            __builtin_amdgcn_s_setprio(1);
            s0 = __builtin_amdgcn_mfma_f32_32x32x16_bf16(k02, qf2, s0, 0,0,0);
            s1 = __builtin_amdgcn_mfma_f32_32x32x16_bf16(k12, qf2, s1, 0,0,0);
            s0 = __builtin_amdgcn_mfma_f32_32x32x16_bf16(k03, qf3, s0, 0,0,0);
            s1 = __builtin_amdgcn_mfma_f32_32x32x16_bf16(k13, qf3, s1, 0,0,0);
            __builtin_amdgcn_s_setprio(0);
        }

        // ---- row max (4 parallel max3 chains) ----
        float ca = max3_(s0[0], s0[1], s0[2]);
        ca = max3_(ca, s0[3], s0[4]);
        ca = max3_(ca, s0[5], s0[6]);
        ca = fmaxf(ca, s0[7]);
        float cb = max3_(s0[8], s0[9], s0[10]);
        cb = max3_(cb, s0[11], s0[12]);
        cb = max3_(cb, s0[13], s0[14]);
        cb = fmaxf(cb, s0[15]);
        float cc = max3_(s1[0], s1[1], s1[2]);
        cc = max3_(cc, s1[3], s1[4]);
        cc = max3_(cc, s1[5], s1[6]);
        cc = fmaxf(cc, s1[7]);
        float cd = max3_(s1[8], s1[9], s1[10]);
        cd = max3_(cd, s1[11], s1[12]);
        cd = max3_(cd, s1[13], s1[14]);
        cd = fmaxf(cd, s1[15]);
        float pm = fmaxf(max3_(ca, cb, cc), cd);
        pm = fmaxf(pm, __shfl_xor(pm, 32, 64));
        if (__any(pm > m_i + THR2)) {
            float mn = fmaxf(m_i, pm);
            float corr = exp2_(m_i - mn);
            m_i = mn;
            l_i *= corr;
            #pragma unroll
            for (int r=0;r<16;++r){
                float cbc = __shfl(corr, ((r&3)+8*(r>>2)) + 4*hi, 64);
                o0[r] *= cbc; o1[r] *= cbc;
            }
        }

        // ---- exponentiate + tree row-sum ----
        #pragma unroll
        for (int r=0;r<16;++r) s0[r] = exp2_(s0[r]-m_i);
        #pragma unroll
        for (int r=0;r<16;++r) s1[r] = exp2_(s1[r]-m_i);
        {
            float r0 = s0[0]+s0[4],  r1 = s0[1]+s0[5];
            float r2 = s0[2]+s0[6],  r3 = s0[3]+s0[7];
            float r4 = s1[0]+s1[4],  r5 = s1[1]+s1[5];
            float r6 = s1[2]+s1[6],  r7 = s1[3]+s1[7];
            r0 += s0[8]+s0[12];  r1 += s0[9]+s0[13];
            r2 += s0[10]+s0[14]; r3 += s0[11]+s0[15];
            r4 += s1[8]+s1[12];  r5 += s1[9]+s1[13];
            r6 += s1[10]+s1[14]; r7 += s1[11]+s1[15];
            float rs = ((r0+r1)+(r2+r3)) + ((r4+r5)+(r6+r7));
            rs += __shfl_xor(rs, 32, 64);
            l_i += rs;
        }

        // ---- P-frags in-register: cvt_pk pairs + permlane32_swap ----
        unsigned a0 = cvtpk(s0[0], s0[1]),  a1 = cvtpk(s0[2], s0[3]);
        unsigned b0 = cvtpk(s0[4], s0[5]),  b1 = cvtpk(s0[6], s0[7]);
        pswap(a0, b0); pswap(a1, b1);
        unsigned c0 = cvtpk(s0[8], s0[9]),  c1 = cvtpk(s0[10], s0[11]);
        unsigned d0 = cvtpk(s0[12], s0[13]),d1 = cvtpk(s0[14], s0[15]);
        pswap(c0, d0); pswap(c1, d1);
        unsigned e0 = cvtpk(s1[0], s1[1]),  e1 = cvtpk(s1[2], s1[3]);
        unsigned f0 = cvtpk(s1[4], s1[5]),  f1 = cvtpk(s1[6], s1[7]);
        pswap(e0, f0); pswap(e1, f1);
        unsigned g0 = cvtpk(s1[8], s1[9]),  g1 = cvtpk(s1[10], s1[11]);
        unsigned h0 = cvtpk(s1[12], s1[13]),h1 = cvtpk(s1[14], s1[15]);
        pswap(g0, h0); pswap(g1, h1);
        union { u32x4 u; s8v s; } pf0, pf1, pf2, pf3;
        pf0.u = (u32x4){a0, a1, b0, b1};
        pf1.u = (u32x4){c0, c1, d0, d1};
        pf2.u = (u32x4){e0, e1, f0, f1};
        pf3.u = (u32x4){g0, g1, h0, h1};

        // ---- O += P @ V, 2 sub-phases (4 V-frags live) ----
        {
            s8v v00 = *(const s8v*)(vb_ + swz(q,    0*2+hi));
            s8v v01 = *(const s8v*)(vb_ + swz(q,    1*2+hi));
            s8v v10 = *(const s8v*)(vb_ + swz(32+q, 0*2+hi));
            s8v v11 = *(const s8v*)(vb_ + swz(32+q, 1*2+hi));
            __builtin_amdgcn_s_setprio(1);
            o0 = __builtin_amdgcn_mfma_f32_32x32x16_bf16(pf0.s, v00, o0, 0,0,0);
            o1 = __builtin_amdgcn_mfma_f32_32x32x16_bf16(pf0.s, v10, o1, 0,0,0);
            o0 = __builtin_amdgcn_mfma_f32_32x32x16_bf16(pf1.s, v01, o0, 0,0,0);
            o1 = __builtin_amdgcn_mfma_f32_32x32x16_bf16(pf1.s, v11, o1, 0,0,0);
            __builtin_amdgcn_s_setprio(0);
        }
        {
            s8v v02 = *(const s8v*)(vb_ + swz(q,    2*2+hi));
            s8v v03 = *(const s8v*)(vb_ + swz(q,    3*2+hi));
            s8v v12 = *(const s8v*)(vb_ + swz(32+q, 2*2+hi));
            s8v v13 = *(const s8v*)(vb_ + swz(32+q, 3*2+hi));
            __builtin_amdgcn_s_setprio(1);
            o0 = __builtin_amdgcn_mfma_f32_32x32x16_bf16(pf2.s, v02, o0, 0,0,0);
            o1 = __builtin_amdgcn_mfma_f32_32x32x16_bf16(pf2.s, v12, o1, 0,0,0);
            o0 = __builtin_amdgcn_mfma_f32_32x32x16_bf16(pf3.s, v03, o0, 0,0,0);
            o1 = __builtin_amdgcn_mfma_f32_32x32x16_bf16(pf3.s, v13, o1, 0,0,0);
            __builtin_amdgcn_s_setprio(0);
        }
        cur ^= 1;
    }

    #pragma unroll
    for (int r=0;r<16;++r){
        int qrow = ((r&3)+8*(r>>2)) + 4*hi;
        float lb = __shfl(l_i, qrow, 64);
        float sc = wl / lb;
        size_t row = (size_t)b*S_ + (size_t)qt*128 + wv*32 + qrow;
        accOut[row*D_ + h*DH_ + q]      = f2bf1(o0[r] * sc);
        accOut[row*D_ + h*DH_ + 32 + q] = f2bf1(o1[r] * sc);
    }
}

// ---------------- launch ----------------
extern "C" void kernel_launch(void* const* d_in, const int* in_sizes, int n_in,
                              void* d_out, int out_size, void* d_ws, size_t ws_size,
                              hipStream_t stream)
{
    const float* query = (const float*)d_in[0];
    const float* key   = (const float*)d_in[1];
    const float* value = (const float*)d_in[2];
    const float* Wq = (const float*)d_in[3];  const float* bq = (const float*)d_in[4];
    const float* Wk = (const float*)d_in[5];  const float* bk = (const float*)d_in[6];
    const float* Wv = (const float*)d_in[7];  const float* bv = (const float*)d_in[8];
    const float* Wo = (const float*)d_in[9];  const float* bo = (const float*)d_in[10];
    const float* wlv = (const float*)d_in[11];

    char* w = (char*)d_ws;
    unsigned short* qhb  = (unsigned short*)(w);             // 8 MB [B,H,S,DH]
    unsigned short* khb0 = (unsigned short*)(w + 8388608);   // 8 MB [B,H,S,DH]
    unsigned short* khb1 = (unsigned short*)(w + 16777216);  // 4 MB
    unsigned short* khb2 = (unsigned short*)(w + 20971520);  // 2 MB
    unsigned short* vtb0 = (unsigned short*)(w + 23068672);  // 8 MB [B,H,DH,S]
    unsigned short* vtb1 = (unsigned short*)(w + 31457280);  // 4 MB
    unsigned short* vtb2 = (unsigned short*)(w + 35651584);  // 2 MB
    unsigned short* Wto  = (unsigned short*)(w + 37748736);  // 2 MB
    unsigned short* Wtq  = (unsigned short*)(w + 39845888);  // 2 MB (dead after proj)
    unsigned short* Wtk  = (unsigned short*)(w + 41943040);  // 2 MB (dead after proj)
    unsigned short* Wtv  = (unsigned short*)(w + 44040192);  // 2 MB (dead after proj)
    unsigned short* acc0 = (unsigned short*)(w + 39845888);  // 8 MB, overlaps Wtq..Wtv
    unsigned short* acc1 = (unsigned short*)(w + 48234496);  // 8 MB
    unsigned short* acc2 = (unsigned short*)(w + 56623104);  // 8 MB -> end 65,011,712

    dim3 bb(256);
    wtrans<<<dim3(32,32,4), bb, 0, stream>>>(Wq, Wk, Wv, Wo, Wtq, Wtk, Wtv, Wto);

    const float scale_q = 0.125f * 1.44269504088896f;   // 1/sqrt(DH) * log2(e)
    gemm_qkv3<<<dim3(32, 8, 3), bb, 0, stream>>>(query, key, value,
                                                 Wtq, Wtk, Wtv, bq, bk, bv,
                                                 qhb, khb0, vtb0,
                                                 khb1, khb2, scale_q);

    // V pools: BH*DH*S/8 threads = 524288 -> 2048 blocks, fully coalesced
    pool_v<<<2048, bb, 0, stream>>>(vtb0, vtb1, vtb2);

    attn_mfma13<<<dim3(32, 16, 3), bb, 0, stream>>>(qhb, khb0, khb1, khb2,
                                                    vtb0, vtb1, vtb2, wlv,
                                                    acc0, acc1, acc2);

    gemm_sum<<<dim3(32, 16), bb, 0, stream>>>(acc0, acc1, acc2, Wto, bo, (float*)d_out);
}